// Round 15
// baseline (330.230 us; speedup 1.0000x reference)
//
#include <hip/hip_runtime.h>

#define NN 20000
#define EE 320000
#define FIN 200
#define HH 128
#define CC 10
#define GG 100
#define BN_EPS 1e-5f
#define RPB 80          // rows per gemm block; 250 blocks x 80 = 20000

typedef __attribute__((ext_vector_type(8))) short bf16x8;
typedef __attribute__((ext_vector_type(4))) float f32x4;

__device__ __forceinline__ ushort bf16rn(float x) {
    uint u = __float_as_uint(x);
    u += 0x7FFFu + ((u >> 16) & 1u);
    return (ushort)(u >> 16);
}

#define F4ADD(d, s) { d.x += s.x; d.y += s.y; d.z += s.z; d.w += s.w; }

// 8-deep-unrolled edge aggregation: 8 independent 512B row loads in flight
// (gathers are latency-bound: R14 gather_bn 48.8us @ 6% VALU, 16% HBM).
__device__ __forceinline__
float4 edge_gather(const float* __restrict__ base, const float* __restrict__ T1,
                   const int* __restrict__ eidx, int n, int ln, int e0, int e1)
{
    float4 a0 = *(const float4*)&base[(size_t)n * HH + ln * 4];
    float4 a1 = {0,0,0,0}, a2 = {0,0,0,0}, a3 = {0,0,0,0};
    float4 a4 = {0,0,0,0}, a5 = {0,0,0,0}, a6 = {0,0,0,0}, a7 = {0,0,0,0};
    int e = e0;
    for (; e + 8 <= e1; e += 8) {
        const int s0 = eidx[e],   s1 = eidx[e+1], s2 = eidx[e+2], s3 = eidx[e+3];
        const int s4 = eidx[e+4], s5 = eidx[e+5], s6 = eidx[e+6], s7 = eidx[e+7];
        const float4 v0 = *(const float4*)&T1[(size_t)s0 * HH + ln * 4];
        const float4 v1 = *(const float4*)&T1[(size_t)s1 * HH + ln * 4];
        const float4 v2 = *(const float4*)&T1[(size_t)s2 * HH + ln * 4];
        const float4 v3 = *(const float4*)&T1[(size_t)s3 * HH + ln * 4];
        const float4 v4 = *(const float4*)&T1[(size_t)s4 * HH + ln * 4];
        const float4 v5 = *(const float4*)&T1[(size_t)s5 * HH + ln * 4];
        const float4 v6 = *(const float4*)&T1[(size_t)s6 * HH + ln * 4];
        const float4 v7 = *(const float4*)&T1[(size_t)s7 * HH + ln * 4];
        F4ADD(a0, v0); F4ADD(a1, v1); F4ADD(a2, v2); F4ADD(a3, v3);
        F4ADD(a4, v4); F4ADD(a5, v5); F4ADD(a6, v6); F4ADD(a7, v7);
    }
    if (e + 4 <= e1) {
        const int s0 = eidx[e], s1 = eidx[e+1], s2 = eidx[e+2], s3 = eidx[e+3];
        const float4 v0 = *(const float4*)&T1[(size_t)s0 * HH + ln * 4];
        const float4 v1 = *(const float4*)&T1[(size_t)s1 * HH + ln * 4];
        const float4 v2 = *(const float4*)&T1[(size_t)s2 * HH + ln * 4];
        const float4 v3 = *(const float4*)&T1[(size_t)s3 * HH + ln * 4];
        F4ADD(a0, v0); F4ADD(a1, v1); F4ADD(a2, v2); F4ADD(a3, v3);
        e += 4;
    }
    for (; e < e1; ++e) {
        const int s = eidx[e];
        const float4 v = *(const float4*)&T1[(size_t)s * HH + ln * 4];
        F4ADD(a0, v);
    }
    float4 r;
    r.x = ((a0.x + a1.x) + (a2.x + a3.x)) + ((a4.x + a5.x) + (a6.x + a7.x));
    r.y = ((a0.y + a1.y) + (a2.y + a3.y)) + ((a4.y + a5.y) + (a6.y + a7.y));
    r.z = ((a0.z + a1.z) + (a2.z + a3.z)) + ((a4.z + a5.z) + (a6.z + a7.z));
    r.w = ((a0.w + a1.w) + (a2.w + a3.w)) + ((a4.w + a5.w) + (a6.w + a7.w));
    return r;
}

// Fragment-major packing (verified R11/R12):
// elem (r,k) -> ((r>>4)*(K/32) + (k>>5))*512 + (((k>>3)&3)*16 + (r&15))*8 + (k&7)

// ---------------------------------------------------------------------------
// Packed W-in-registers GEMM (verified R12)
// ---------------------------------------------------------------------------
template<int KSTEPS>
__global__ __launch_bounds__(512)
void gemm_pk(const ushort* __restrict__ Aph, const ushort* __restrict__ Apl,
             const ushort* __restrict__ Wph, const ushort* __restrict__ Wpl,
             const float* __restrict__ bias,
             float* __restrict__ Croot, float* __restrict__ Crel)
{
    const int wid  = threadIdx.x >> 6;
    const int lane = threadIdx.x & 63;
    const int l15  = lane & 15;
    const int matsel = wid >> 2;
    const int ncol = (wid & 3) * 32;
    const int wrg0 = matsel * 8 + (ncol >> 4);
    const int rowb = (lane >> 4) * 4;
    const int rbase0 = blockIdx.x * RPB;

    bf16x8 wh[2][KSTEPS], wl[2][KSTEPS];
    #pragma unroll
    for (int nf = 0; nf < 2; ++nf) {
        const size_t wbase = (size_t)(wrg0 + nf) * KSTEPS * 512;
        #pragma unroll
        for (int ks = 0; ks < KSTEPS; ++ks) {
            wh[nf][ks] = *(const bf16x8*)&Wph[wbase + (size_t)(ks * 64 + lane) * 8];
            wl[nf][ks] = *(const bf16x8*)&Wpl[wbase + (size_t)(ks * 64 + lane) * 8];
        }
    }
    float bv[2] = {0.f, 0.f};
    if (matsel == 0 && bias) { bv[0] = bias[ncol + l15]; bv[1] = bias[ncol + 16 + l15]; }
    float* __restrict__ C = matsel ? Crel : Croot;

    for (int ch = 0; ch < RPB; ch += 16) {
        const size_t abase = (size_t)((rbase0 + ch) >> 4) * KSTEPS * 512;
        f32x4 acc[2] = {};
        #pragma unroll
        for (int ks = 0; ks < KSTEPS; ++ks) {
            const bf16x8 ah = *(const bf16x8*)&Aph[abase + (size_t)(ks * 64 + lane) * 8];
            const bf16x8 al = *(const bf16x8*)&Apl[abase + (size_t)(ks * 64 + lane) * 8];
            #pragma unroll
            for (int nf = 0; nf < 2; ++nf) {
                acc[nf] = __builtin_amdgcn_mfma_f32_16x16x32_bf16(ah, wh[nf][ks], acc[nf], 0, 0, 0);
                acc[nf] = __builtin_amdgcn_mfma_f32_16x16x32_bf16(al, wh[nf][ks], acc[nf], 0, 0, 0);
                acc[nf] = __builtin_amdgcn_mfma_f32_16x16x32_bf16(ah, wl[nf][ks], acc[nf], 0, 0, 0);
            }
        }
        #pragma unroll
        for (int nf = 0; nf < 2; ++nf) {
            const int col = ncol + nf * 16 + l15;   // LOCAL column (0..127)
            #pragma unroll
            for (int j = 0; j < 4; ++j) {
                const int row = rbase0 + ch + rowb + j;
                C[(size_t)row * HH + col] = acc[nf][j] + bv[nf];
            }
        }
    }
}

// ---------------------------------------------------------------------------
// Layer-5 packed concat-GEMM (verified R12)
// ---------------------------------------------------------------------------
__global__ __launch_bounds__(512)
void gemm_pk4(const ushort* __restrict__ X1h, const ushort* __restrict__ X1l,
              const ushort* __restrict__ X2h, const ushort* __restrict__ X2l,
              const ushort* __restrict__ X3h, const ushort* __restrict__ X3l,
              const ushort* __restrict__ X4h, const ushort* __restrict__ X4l,
              const ushort* __restrict__ Wph, const ushort* __restrict__ Wpl,
              const float* __restrict__ bias,
              float* __restrict__ Croot, float* __restrict__ Crel)
{
    const int wid  = threadIdx.x >> 6;
    const int lane = threadIdx.x & 63;
    const int l15  = lane & 15;
    const int matsel = wid >> 2;
    const int ncol = (wid & 3) * 32;
    const int wrg0 = matsel * 8 + (ncol >> 4);
    const int rowb = (lane >> 4) * 4;
    const int rbase0 = blockIdx.x * RPB;
    const ushort* const Ahs[4] = {X1h, X2h, X3h, X4h};
    const ushort* const Als[4] = {X1l, X2l, X3l, X4l};

    f32x4 acc[5][2] = {};
    #pragma unroll
    for (int src = 0; src < 4; ++src) {
        const ushort* __restrict__ Ah_ = Ahs[src];
        const ushort* __restrict__ Al_ = Als[src];
        bf16x8 wh[2][4], wl[2][4];
        #pragma unroll
        for (int nf = 0; nf < 2; ++nf) {
            const size_t wbase = ((size_t)(wrg0 + nf) * 16 + src * 4) * 512;
            #pragma unroll
            for (int ks = 0; ks < 4; ++ks) {
                wh[nf][ks] = *(const bf16x8*)&Wph[wbase + (size_t)(ks * 64 + lane) * 8];
                wl[nf][ks] = *(const bf16x8*)&Wpl[wbase + (size_t)(ks * 64 + lane) * 8];
            }
        }
        #pragma unroll
        for (int ch = 0; ch < 5; ++ch) {
            const size_t abase = (size_t)((rbase0 + ch * 16) >> 4) * 4 * 512;
            #pragma unroll
            for (int ks = 0; ks < 4; ++ks) {
                const bf16x8 ah = *(const bf16x8*)&Ah_[abase + (size_t)(ks * 64 + lane) * 8];
                const bf16x8 al = *(const bf16x8*)&Al_[abase + (size_t)(ks * 64 + lane) * 8];
                #pragma unroll
                for (int nf = 0; nf < 2; ++nf) {
                    acc[ch][nf] = __builtin_amdgcn_mfma_f32_16x16x32_bf16(ah, wh[nf][ks], acc[ch][nf], 0, 0, 0);
                    acc[ch][nf] = __builtin_amdgcn_mfma_f32_16x16x32_bf16(al, wh[nf][ks], acc[ch][nf], 0, 0, 0);
                    acc[ch][nf] = __builtin_amdgcn_mfma_f32_16x16x32_bf16(ah, wl[nf][ks], acc[ch][nf], 0, 0, 0);
                }
            }
        }
    }
    float bv[2] = {0.f, 0.f};
    if (matsel == 0 && bias) { bv[0] = bias[ncol + l15]; bv[1] = bias[ncol + 16 + l15]; }
    float* __restrict__ C = matsel ? Crel : Croot;
    #pragma unroll
    for (int ch = 0; ch < 5; ++ch) {
        #pragma unroll
        for (int nf = 0; nf < 2; ++nf) {
            const int col = ncol + nf * 16 + l15;
            #pragma unroll
            for (int j = 0; j < 4; ++j) {
                const int row = rbase0 + ch * 16 + rowb + j;
                C[(size_t)row * HH + col] = acc[ch][nf][j] + bv[nf];
            }
        }
    }
}

// ---------------------------------------------------------------------------
// all 5 weight splits in ONE dispatch (verified R14)
// ---------------------------------------------------------------------------
__global__ __launch_bounds__(256)
void split_all(const float* __restrict__ r1, const float* __restrict__ e1,
               const float* __restrict__ r2, const float* __restrict__ e2,
               const float* __restrict__ r3, const float* __restrict__ e3,
               const float* __restrict__ r4, const float* __restrict__ e4,
               const float* __restrict__ r5, const float* __restrict__ e5,
               ushort* __restrict__ W1h, ushort* __restrict__ W1l,
               ushort* __restrict__ W2h, ushort* __restrict__ W2l,
               ushort* __restrict__ W3h, ushort* __restrict__ W3l,
               ushort* __restrict__ W4h, ushort* __restrict__ W4l,
               ushort* __restrict__ W5h, ushort* __restrict__ W5l)
{
    const int b = blockIdx.x;
    const float *Wroot, *Wrel; int K, Kp, base; ushort *Wh, *Wl;
    if (b < 224)      { Wroot = r1; Wrel = e1; K = FIN; Kp = 224; Wh = W1h; Wl = W1l; base = 0; }
    else if (b < 352) { Wroot = r2; Wrel = e2; K = 128; Kp = 128; Wh = W2h; Wl = W2l; base = 224; }
    else if (b < 480) { Wroot = r3; Wrel = e3; K = 128; Kp = 128; Wh = W3h; Wl = W3l; base = 352; }
    else if (b < 608) { Wroot = r4; Wrel = e4; K = 128; Kp = 128; Wh = W4h; Wl = W4l; base = 480; }
    else              { Wroot = r5; Wrel = e5; K = 512; Kp = 512; Wh = W5h; Wl = W5l; base = 608; }
    const int i = (b - base) * 256 + threadIdx.x;
    const int row = i / Kp, col = i - row * Kp;
    float v = 0.f;
    if (col < K) v = (row < 128) ? Wroot[row * K + col] : Wrel[(row - 128) * K + col];
    const ushort h = bf16rn(v);
    const float hf = __uint_as_float((uint)h << 16);
    const int ksteps = Kp >> 5;
    const size_t addr = ((size_t)(row >> 4) * ksteps + (col >> 5)) * 512
                      + (size_t)(((col >> 3) & 3) * 16 + (row & 15)) * 8 + (col & 7);
    Wh[addr] = h;
    Wl[addr] = bf16rn(v - hf);
}

// ---------------------------------------------------------------------------
// pack layer-1 input (verified R12)
// ---------------------------------------------------------------------------
__global__ __launch_bounds__(448)
void pack_x(const float* __restrict__ x, ushort* __restrict__ Xh, ushort* __restrict__ Xl)
{
    const int t = threadIdx.x;
    const int n = blockIdx.x * 16 + (t & 15);
    const int o = t >> 4;                   // k-octet 0..27
    float v[8];
    if (o < 25) {
        const float4 a = *(const float4*)&x[(size_t)n * FIN + o * 8];
        const float4 b = *(const float4*)&x[(size_t)n * FIN + o * 8 + 4];
        v[0]=a.x; v[1]=a.y; v[2]=a.z; v[3]=a.w; v[4]=b.x; v[5]=b.y; v[6]=b.z; v[7]=b.w;
    } else {
        #pragma unroll
        for (int j = 0; j < 8; ++j) v[j] = 0.f;
    }
    bf16x8 h, l;
    #pragma unroll
    for (int j = 0; j < 8; ++j) {
        const ushort hh = bf16rn(v[j]);
        h[j] = (short)hh;
        l[j] = (short)bf16rn(v[j] - __uint_as_float((uint)hh << 16));
    }
    const size_t addr = ((size_t)(n >> 4) * 7 + (o >> 2)) * 512
                      + (size_t)((o & 3) * 16 + (n & 15)) * 8;
    *(bf16x8*)&Xh[addr] = h;
    *(bf16x8*)&Xl[addr] = l;
}

// ---------------------------------------------------------------------------
// CSR build (verified R12)
// ---------------------------------------------------------------------------
__global__ void hist_k(const int* __restrict__ ei, int* __restrict__ deg)
{
    int e = blockIdx.x * blockDim.x + threadIdx.x;
    if (e < EE) atomicAdd(&deg[ei[EE + e]], 1);
}

__global__ __launch_bounds__(1024)
void scan_k(const int* __restrict__ deg, int* __restrict__ row_ptr,
            int* __restrict__ pos)
{
    __shared__ int part[1024];
    const int t = threadIdx.x;
    const int chunk = (NN + 1023) / 1024;
    const int i0 = t * chunk;
    const int i1 = min(i0 + chunk, NN);
    int s = 0;
    for (int i = i0; i < i1; ++i) s += deg[i];
    part[t] = s;
    __syncthreads();
    for (int off = 1; off < 1024; off <<= 1) {
        int v = (t >= off) ? part[t - off] : 0;
        __syncthreads();
        part[t] += v;
        __syncthreads();
    }
    int run = (t == 0) ? 0 : part[t - 1];
    for (int i = i0; i < i1; ++i) {
        const int d = deg[i];
        row_ptr[i] = run;
        pos[i] = run;
        run += d;
    }
    if (t == 0) row_ptr[NN] = part[1023];
}

__global__ void fill_k(const int* __restrict__ ei, int* __restrict__ pos,
                       int* __restrict__ eidx)
{
    int e = blockIdx.x * blockDim.x + threadIdx.x;
    if (e < EE) {
        const int slot = atomicAdd(&pos[ei[EE + e]], 1);
        eidx[slot] = ei[e];
    }
}

// one zero pass over deg (ints) + STATS/POOL (floats)
__global__ void zero2_k(int* __restrict__ deg, float* __restrict__ sp, int n1, int n2)
{
    int i = blockIdx.x * blockDim.x + threadIdx.x;
    if (i < n1) deg[i] = 0;
    else if (i < n1 + n2) sp[i - n1] = 0.f;
}

// ---------------------------------------------------------------------------
// gather v4: 8-deep MLP edge loop + LDS-staged packed writes (R12 structure)
// ---------------------------------------------------------------------------
__global__ __launch_bounds__(512)
void gather_pk(const float* __restrict__ base, const float* __restrict__ T1,
               const int* __restrict__ row_ptr, const int* __restrict__ eidx,
               ushort* __restrict__ Xh, ushort* __restrict__ Xl)
{
    __shared__ ushort lds_h[16][136];
    __shared__ ushort lds_l[16][136];
    const int t   = threadIdx.x;
    const int grp = t >> 5;
    const int ln  = t & 31;
    const int n   = blockIdx.x * 16 + grp;

    const float4 r = edge_gather(base, T1, eidx, n, ln, row_ptr[n], row_ptr[n + 1]);
    float v[4];
    v[0] = fmaxf(r.x, 0.f); v[1] = fmaxf(r.y, 0.f);
    v[2] = fmaxf(r.z, 0.f); v[3] = fmaxf(r.w, 0.f);
    ushort4 h4, l4;
    {
        ushort hh; float hf;
        hh = bf16rn(v[0]); hf = __uint_as_float((uint)hh << 16); h4.x = hh; l4.x = bf16rn(v[0] - hf);
        hh = bf16rn(v[1]); hf = __uint_as_float((uint)hh << 16); h4.y = hh; l4.y = bf16rn(v[1] - hf);
        hh = bf16rn(v[2]); hf = __uint_as_float((uint)hh << 16); h4.z = hh; l4.z = bf16rn(v[2] - hf);
        hh = bf16rn(v[3]); hf = __uint_as_float((uint)hh << 16); h4.w = hh; l4.w = bf16rn(v[3] - hf);
    }
    *(ushort4*)&lds_h[grp][ln * 4] = h4;
    *(ushort4*)&lds_l[grp][ln * 4] = l4;
    __syncthreads();

    const int nl = t & 15;
    const int o  = (t >> 4) & 15;
    const size_t addr = ((size_t)blockIdx.x * 4 + (o >> 2)) * 512
                      + (size_t)((o & 3) * 16 + nl) * 8;
    if (t < 256) {
        *(uint4*)&Xh[addr] = *(const uint4*)&lds_h[nl][o * 8];
    } else {
        *(uint4*)&Xl[addr] = *(const uint4*)&lds_l[nl][o * 8];
    }
}

// ---------------------------------------------------------------------------
// layer-5 gather FUSED with BN-stats + pooling; 512 thr, 16 nodes, 1 pass.
// Phase-2 reduction 3-way parallel: sum / sumsq / pool in disjoint ranges.
// ---------------------------------------------------------------------------
__global__ __launch_bounds__(512)
void gather_bn(const float* __restrict__ base, const float* __restrict__ T1,
               const int* __restrict__ row_ptr, const int* __restrict__ eidx,
               const int* __restrict__ batch,
               float* __restrict__ stats, float* __restrict__ pool)
{
    __shared__ float vals[16][132];
    __shared__ int bg[16];
    const int t   = threadIdx.x;
    const int grp = t >> 5;
    const int ln  = t & 31;
    const int n0  = blockIdx.x * 16;
    const int n   = n0 + grp;

    const float4 r = edge_gather(base, T1, eidx, n, ln, row_ptr[n], row_ptr[n + 1]);
    vals[grp][ln * 4 + 0] = r.x;
    vals[grp][ln * 4 + 1] = r.y;
    vals[grp][ln * 4 + 2] = r.z;
    vals[grp][ln * 4 + 3] = r.w;
    if (t < 16) bg[t] = batch[n0 + t];
    __syncthreads();

    if (t < 128) {
        float s = 0.f;
        #pragma unroll
        for (int rr = 0; rr < 16; ++rr) s += vals[rr][t];
        atomicAdd(&stats[t], s);
    } else if (t < 256) {
        const int f = t - 128;
        float q = 0.f;
        #pragma unroll
        for (int rr = 0; rr < 16; ++rr) { const float v = vals[rr][f]; q += v * v; }
        atomicAdd(&stats[128 + f], q);
    } else if (t < 384) {
        const int f = t - 256;
        float acc = 0.f;
        int curg = bg[0];
        #pragma unroll
        for (int rr = 0; rr < 16; ++rr) {
            const int g = bg[rr];
            if (g != curg) {
                atomicAdd(&pool[(size_t)curg * HH + f], acc);
                acc = 0.f; curg = g;
            }
            acc += vals[rr][f];
        }
        atomicAdd(&pool[(size_t)curg * HH + f], acc);
    }
}

// BN affine on pooled means + linear head (verified R12)
__global__ __launch_bounds__(128)
void finalize(const float* __restrict__ stats, const float* __restrict__ pool,
              const int* __restrict__ batch,
              const float* __restrict__ gamma, const float* __restrict__ beta,
              const float* __restrict__ lin_w, const float* __restrict__ lin_b,
              float* __restrict__ out)
{
    const int g = blockIdx.x, f = threadIdx.x;
    __shared__ int seg[2];
    if (f < 2) {
        const int target = g + f;
        int lo = 0, hi = NN;
        while (lo < hi) {
            const int mid = (lo + hi) >> 1;
            if (batch[mid] < target) lo = mid + 1; else hi = mid;
        }
        seg[f] = lo;
    }
    __syncthreads();
    const float c   = (float)(seg[1] - seg[0]);
    const float mu  = stats[f] * (1.0f / NN);
    const float var = stats[128 + f] * (1.0f / NN) - mu * mu;
    const float scale = gamma[f] * rsqrtf(var + BN_EPS);
    const float pm = pool[(size_t)g * HH + f] / fmaxf(c, 1.0f);
    __shared__ float sh[128];
    sh[f] = (pm - mu) * scale + beta[f];
    __syncthreads();
    if (f < CC) {
        float s = lin_b[f];
        #pragma unroll 8
        for (int k = 0; k < HH; ++k) s += sh[k] * lin_w[f * HH + k];
        out[(size_t)g * CC + f] = s;
    }
}

extern "C" void kernel_launch(void* const* d_in, const int* in_sizes, int n_in,
                              void* d_out, int out_size, void* d_ws, size_t ws_size,
                              hipStream_t stream)
{
    const float* x       = (const float*)d_in[0];
    const int*   ei      = (const int*)d_in[1];
    const int*   batch   = (const int*)d_in[2];
    const float* w1_rel  = (const float*)d_in[3];
    const float* w1_root = (const float*)d_in[4];
    const float* b1      = (const float*)d_in[5];
    const float* w2_rel  = (const float*)d_in[6];
    const float* w2_root = (const float*)d_in[7];
    const float* b2      = (const float*)d_in[8];
    const float* w3_rel  = (const float*)d_in[9];
    const float* w3_root = (const float*)d_in[10];
    const float* b3      = (const float*)d_in[11];
    const float* w4_rel  = (const float*)d_in[12];
    const float* w4_root = (const float*)d_in[13];
    const float* b4      = (const float*)d_in[14];
    const float* w5_rel  = (const float*)d_in[15];   // [128, 512]
    const float* w5_root = (const float*)d_in[16];   // [128, 512]
    const float* b5      = (const float*)d_in[17];
    const float* gamma   = (const float*)d_in[18];
    const float* beta    = (const float*)d_in[19];
    const float* lin_w   = (const float*)d_in[20];
    const float* lin_b   = (const float*)d_in[21];
    float* out = (float*)d_out;

    const size_t NH = (size_t)NN * HH;   // 2,560,000
    float*  XR  = (float*)d_ws;
    float*  T1  = XR + NH;
    ushort* X1h = (ushort*)(T1 + NH);
    ushort* X1l = X1h + NH;
    ushort* X2h = X1l + NH;
    ushort* X2l = X2h + NH;
    ushort* X3h = X2l + NH;
    ushort* X3l = X3h + NH;
    ushort* X4h = X3l + NH;
    ushort* X4l = X4h + NH;
    const int K1P = 224;
    ushort* W1h = X4l + NH;
    ushort* W1l = W1h + 256 * K1P;
    ushort* W2h = W1l + 256 * K1P;
    ushort* W2l = W2h + 256 * 128;
    ushort* W3h = W2l + 256 * 128;
    ushort* W3l = W3h + 256 * 128;
    ushort* W4h = W3l + 256 * 128;
    ushort* W4l = W4h + 256 * 128;
    ushort* W5h = W4l + 256 * 128;
    ushort* W5l = W5h + 256 * 512;
    float*  STATS = (float*)(W5l + 256 * 512);   // 256
    float*  POOL  = STATS + 256;                 // GG*HH
    int* row_ptr = (int*)(POOL + (size_t)GG * HH);
    int* pos     = row_ptr + (NN + 1);
    int* deg     = pos + NN;
    int* eidx    = deg + NN;
    const size_t need = (size_t)(eidx + EE) - (size_t)d_ws;
    if (ws_size < need) return;

    // packed layer-1 input aliases X2h..X3l (dead once L1 GEMM completes)
    ushort* XPh = X2h;
    ushort* XPl = X2h + (size_t)NN * K1P;

    const dim3 blk(256);
    const int ggw   = NN / RPB;             // 250 blocks x 512 thr
    const int gedge = (EE + 255) / 256;
    const int ggpk  = NN / 16;              // 1250 blocks

    // single zero pass: deg (ints) + STATS/POOL (floats)
    const int nz = NN + 256 + GG * HH;
    zero2_k<<<(nz + 255) / 256, blk, 0, stream>>>(deg, STATS, NN, 256 + GG * HH);

    // CSR build
    hist_k<<<gedge, blk, 0, stream>>>(ei, deg);
    scan_k<<<1, dim3(1024), 0, stream>>>(deg, row_ptr, pos);
    fill_k<<<gedge, blk, 0, stream>>>(ei, pos, eidx);

    // all weight splits in one dispatch + layer-1 input pack
    split_all<<<1120, blk, 0, stream>>>(w1_root, w1_rel, w2_root, w2_rel,
                                        w3_root, w3_rel, w4_root, w4_rel,
                                        w5_root, w5_rel,
                                        W1h, W1l, W2h, W2l, W3h, W3l,
                                        W4h, W4l, W5h, W5l);
    pack_x<<<ggpk, dim3(448), 0, stream>>>(x, XPh, XPl);

    // layer 1 (K=224 packed)
    gemm_pk<7><<<ggw, dim3(512), 0, stream>>>(XPh, XPl, W1h, W1l, b1, XR, T1);
    gather_pk<<<ggpk, dim3(512), 0, stream>>>(XR, T1, row_ptr, eidx, X1h, X1l);
    // layers 2-4 (K=128 packed)
    gemm_pk<4><<<ggw, dim3(512), 0, stream>>>(X1h, X1l, W2h, W2l, b2, XR, T1);
    gather_pk<<<ggpk, dim3(512), 0, stream>>>(XR, T1, row_ptr, eidx, X2h, X2l);
    gemm_pk<4><<<ggw, dim3(512), 0, stream>>>(X2h, X2l, W3h, W3l, b3, XR, T1);
    gather_pk<<<ggpk, dim3(512), 0, stream>>>(XR, T1, row_ptr, eidx, X3h, X3l);
    gemm_pk<4><<<ggw, dim3(512), 0, stream>>>(X3h, X3l, W4h, W4l, b4, XR, T1);
    gather_pk<<<ggpk, dim3(512), 0, stream>>>(XR, T1, row_ptr, eidx, X4h, X4l);
    // layer 5: packed concat GEMM, then fused gather+BN+pool (X5 never stored)
    gemm_pk4<<<ggw, dim3(512), 0, stream>>>(X1h, X1l, X2h, X2l, X3h, X3l, X4h, X4l,
                                            W5h, W5l, b5, XR, T1);
    gather_bn<<<ggpk, dim3(512), 0, stream>>>(XR, T1, row_ptr, eidx, batch, STATS, POOL);

    // epilogue
    finalize<<<GG, dim3(128), 0, stream>>>(STATS, POOL, batch, gamma, beta, lin_w, lin_b, out);
}

// Round 16
// 321.090 us; speedup vs baseline: 1.0285x; 1.0285x over previous
//
#include <hip/hip_runtime.h>

#define NN 20000
#define EE 320000
#define FIN 200
#define HH 128
#define CC 10
#define GG 100
#define BN_EPS 1e-5f
#define RPB 80          // rows per gemm block; 250 blocks x 80 = 20000

typedef __attribute__((ext_vector_type(8))) short bf16x8;
typedef __attribute__((ext_vector_type(4))) float f32x4;

__device__ __forceinline__ ushort bf16rn(float x) {
    uint u = __float_as_uint(x);
    u += 0x7FFFu + ((u >> 16) & 1u);
    return (ushort)(u >> 16);
}

#define F4ADD(d, s) { d.x += s.x; d.y += s.y; d.z += s.z; d.w += s.w; }

// 4-deep-unrolled edge aggregation (R14-proven; 8-deep regressed in R15:
// deg~16 -> tail overhead + VGPR pressure outweighed extra MLP).
__device__ __forceinline__
float4 edge_gather(const float* __restrict__ base, const float* __restrict__ T1,
                   const int* __restrict__ eidx, int n, int ln, int e0, int e1)
{
    float4 a0 = *(const float4*)&base[(size_t)n * HH + ln * 4];
    float4 a1 = {0,0,0,0}, a2 = {0,0,0,0}, a3 = {0,0,0,0};
    int e = e0;
    for (; e + 4 <= e1; e += 4) {
        const int s0 = eidx[e], s1 = eidx[e+1], s2 = eidx[e+2], s3 = eidx[e+3];
        const float4 v0 = *(const float4*)&T1[(size_t)s0 * HH + ln * 4];
        const float4 v1 = *(const float4*)&T1[(size_t)s1 * HH + ln * 4];
        const float4 v2 = *(const float4*)&T1[(size_t)s2 * HH + ln * 4];
        const float4 v3 = *(const float4*)&T1[(size_t)s3 * HH + ln * 4];
        F4ADD(a0, v0); F4ADD(a1, v1); F4ADD(a2, v2); F4ADD(a3, v3);
    }
    for (; e < e1; ++e) {
        const int s = eidx[e];
        const float4 v = *(const float4*)&T1[(size_t)s * HH + ln * 4];
        F4ADD(a0, v);
    }
    float4 r;
    r.x = (a0.x + a1.x) + (a2.x + a3.x);
    r.y = (a0.y + a1.y) + (a2.y + a3.y);
    r.z = (a0.z + a1.z) + (a2.z + a3.z);
    r.w = (a0.w + a1.w) + (a2.w + a3.w);
    return r;
}

// Fragment-major packing (verified R11/R12):
// elem (r,k) -> ((r>>4)*(K/32) + (k>>5))*512 + (((k>>3)&3)*16 + (r&15))*8 + (k&7)

// ---------------------------------------------------------------------------
// Packed W-in-registers GEMM (verified R12)
// ---------------------------------------------------------------------------
template<int KSTEPS>
__global__ __launch_bounds__(512)
void gemm_pk(const ushort* __restrict__ Aph, const ushort* __restrict__ Apl,
             const ushort* __restrict__ Wph, const ushort* __restrict__ Wpl,
             const float* __restrict__ bias,
             float* __restrict__ Croot, float* __restrict__ Crel)
{
    const int wid  = threadIdx.x >> 6;
    const int lane = threadIdx.x & 63;
    const int l15  = lane & 15;
    const int matsel = wid >> 2;
    const int ncol = (wid & 3) * 32;
    const int wrg0 = matsel * 8 + (ncol >> 4);
    const int rowb = (lane >> 4) * 4;
    const int rbase0 = blockIdx.x * RPB;

    bf16x8 wh[2][KSTEPS], wl[2][KSTEPS];
    #pragma unroll
    for (int nf = 0; nf < 2; ++nf) {
        const size_t wbase = (size_t)(wrg0 + nf) * KSTEPS * 512;
        #pragma unroll
        for (int ks = 0; ks < KSTEPS; ++ks) {
            wh[nf][ks] = *(const bf16x8*)&Wph[wbase + (size_t)(ks * 64 + lane) * 8];
            wl[nf][ks] = *(const bf16x8*)&Wpl[wbase + (size_t)(ks * 64 + lane) * 8];
        }
    }
    float bv[2] = {0.f, 0.f};
    if (matsel == 0 && bias) { bv[0] = bias[ncol + l15]; bv[1] = bias[ncol + 16 + l15]; }
    float* __restrict__ C = matsel ? Crel : Croot;

    for (int ch = 0; ch < RPB; ch += 16) {
        const size_t abase = (size_t)((rbase0 + ch) >> 4) * KSTEPS * 512;
        f32x4 acc[2] = {};
        #pragma unroll
        for (int ks = 0; ks < KSTEPS; ++ks) {
            const bf16x8 ah = *(const bf16x8*)&Aph[abase + (size_t)(ks * 64 + lane) * 8];
            const bf16x8 al = *(const bf16x8*)&Apl[abase + (size_t)(ks * 64 + lane) * 8];
            #pragma unroll
            for (int nf = 0; nf < 2; ++nf) {
                acc[nf] = __builtin_amdgcn_mfma_f32_16x16x32_bf16(ah, wh[nf][ks], acc[nf], 0, 0, 0);
                acc[nf] = __builtin_amdgcn_mfma_f32_16x16x32_bf16(al, wh[nf][ks], acc[nf], 0, 0, 0);
                acc[nf] = __builtin_amdgcn_mfma_f32_16x16x32_bf16(ah, wl[nf][ks], acc[nf], 0, 0, 0);
            }
        }
        #pragma unroll
        for (int nf = 0; nf < 2; ++nf) {
            const int col = ncol + nf * 16 + l15;   // LOCAL column (0..127)
            #pragma unroll
            for (int j = 0; j < 4; ++j) {
                const int row = rbase0 + ch + rowb + j;
                C[(size_t)row * HH + col] = acc[nf][j] + bv[nf];
            }
        }
    }
}

// ---------------------------------------------------------------------------
// Layer-5 packed concat-GEMM (verified R12)
// ---------------------------------------------------------------------------
__global__ __launch_bounds__(512)
void gemm_pk4(const ushort* __restrict__ X1h, const ushort* __restrict__ X1l,
              const ushort* __restrict__ X2h, const ushort* __restrict__ X2l,
              const ushort* __restrict__ X3h, const ushort* __restrict__ X3l,
              const ushort* __restrict__ X4h, const ushort* __restrict__ X4l,
              const ushort* __restrict__ Wph, const ushort* __restrict__ Wpl,
              const float* __restrict__ bias,
              float* __restrict__ Croot, float* __restrict__ Crel)
{
    const int wid  = threadIdx.x >> 6;
    const int lane = threadIdx.x & 63;
    const int l15  = lane & 15;
    const int matsel = wid >> 2;
    const int ncol = (wid & 3) * 32;
    const int wrg0 = matsel * 8 + (ncol >> 4);
    const int rowb = (lane >> 4) * 4;
    const int rbase0 = blockIdx.x * RPB;
    const ushort* const Ahs[4] = {X1h, X2h, X3h, X4h};
    const ushort* const Als[4] = {X1l, X2l, X3l, X4l};

    f32x4 acc[5][2] = {};
    #pragma unroll
    for (int src = 0; src < 4; ++src) {
        const ushort* __restrict__ Ah_ = Ahs[src];
        const ushort* __restrict__ Al_ = Als[src];
        bf16x8 wh[2][4], wl[2][4];
        #pragma unroll
        for (int nf = 0; nf < 2; ++nf) {
            const size_t wbase = ((size_t)(wrg0 + nf) * 16 + src * 4) * 512;
            #pragma unroll
            for (int ks = 0; ks < 4; ++ks) {
                wh[nf][ks] = *(const bf16x8*)&Wph[wbase + (size_t)(ks * 64 + lane) * 8];
                wl[nf][ks] = *(const bf16x8*)&Wpl[wbase + (size_t)(ks * 64 + lane) * 8];
            }
        }
        #pragma unroll
        for (int ch = 0; ch < 5; ++ch) {
            const size_t abase = (size_t)((rbase0 + ch * 16) >> 4) * 4 * 512;
            #pragma unroll
            for (int ks = 0; ks < 4; ++ks) {
                const bf16x8 ah = *(const bf16x8*)&Ah_[abase + (size_t)(ks * 64 + lane) * 8];
                const bf16x8 al = *(const bf16x8*)&Al_[abase + (size_t)(ks * 64 + lane) * 8];
                #pragma unroll
                for (int nf = 0; nf < 2; ++nf) {
                    acc[ch][nf] = __builtin_amdgcn_mfma_f32_16x16x32_bf16(ah, wh[nf][ks], acc[ch][nf], 0, 0, 0);
                    acc[ch][nf] = __builtin_amdgcn_mfma_f32_16x16x32_bf16(al, wh[nf][ks], acc[ch][nf], 0, 0, 0);
                    acc[ch][nf] = __builtin_amdgcn_mfma_f32_16x16x32_bf16(ah, wl[nf][ks], acc[ch][nf], 0, 0, 0);
                }
            }
        }
    }
    float bv[2] = {0.f, 0.f};
    if (matsel == 0 && bias) { bv[0] = bias[ncol + l15]; bv[1] = bias[ncol + 16 + l15]; }
    float* __restrict__ C = matsel ? Crel : Croot;
    #pragma unroll
    for (int ch = 0; ch < 5; ++ch) {
        #pragma unroll
        for (int nf = 0; nf < 2; ++nf) {
            const int col = ncol + nf * 16 + l15;
            #pragma unroll
            for (int j = 0; j < 4; ++j) {
                const int row = rbase0 + ch * 16 + rowb + j;
                C[(size_t)row * HH + col] = acc[ch][nf][j] + bv[nf];
            }
        }
    }
}

// ---------------------------------------------------------------------------
// all 5 weight splits in ONE dispatch (verified R14)
// ---------------------------------------------------------------------------
__global__ __launch_bounds__(256)
void split_all(const float* __restrict__ r1, const float* __restrict__ e1,
               const float* __restrict__ r2, const float* __restrict__ e2,
               const float* __restrict__ r3, const float* __restrict__ e3,
               const float* __restrict__ r4, const float* __restrict__ e4,
               const float* __restrict__ r5, const float* __restrict__ e5,
               ushort* __restrict__ W1h, ushort* __restrict__ W1l,
               ushort* __restrict__ W2h, ushort* __restrict__ W2l,
               ushort* __restrict__ W3h, ushort* __restrict__ W3l,
               ushort* __restrict__ W4h, ushort* __restrict__ W4l,
               ushort* __restrict__ W5h, ushort* __restrict__ W5l)
{
    const int b = blockIdx.x;
    const float *Wroot, *Wrel; int K, Kp, base; ushort *Wh, *Wl;
    if (b < 224)      { Wroot = r1; Wrel = e1; K = FIN; Kp = 224; Wh = W1h; Wl = W1l; base = 0; }
    else if (b < 352) { Wroot = r2; Wrel = e2; K = 128; Kp = 128; Wh = W2h; Wl = W2l; base = 224; }
    else if (b < 480) { Wroot = r3; Wrel = e3; K = 128; Kp = 128; Wh = W3h; Wl = W3l; base = 352; }
    else if (b < 608) { Wroot = r4; Wrel = e4; K = 128; Kp = 128; Wh = W4h; Wl = W4l; base = 480; }
    else              { Wroot = r5; Wrel = e5; K = 512; Kp = 512; Wh = W5h; Wl = W5l; base = 608; }
    const int i = (b - base) * 256 + threadIdx.x;
    const int row = i / Kp, col = i - row * Kp;
    float v = 0.f;
    if (col < K) v = (row < 128) ? Wroot[row * K + col] : Wrel[(row - 128) * K + col];
    const ushort h = bf16rn(v);
    const float hf = __uint_as_float((uint)h << 16);
    const int ksteps = Kp >> 5;
    const size_t addr = ((size_t)(row >> 4) * ksteps + (col >> 5)) * 512
                      + (size_t)(((col >> 3) & 3) * 16 + (row & 15)) * 8 + (col & 7);
    Wh[addr] = h;
    Wl[addr] = bf16rn(v - hf);
}

// ---------------------------------------------------------------------------
// pack layer-1 input (verified R12)
// ---------------------------------------------------------------------------
__global__ __launch_bounds__(448)
void pack_x(const float* __restrict__ x, ushort* __restrict__ Xh, ushort* __restrict__ Xl)
{
    const int t = threadIdx.x;
    const int n = blockIdx.x * 16 + (t & 15);
    const int o = t >> 4;                   // k-octet 0..27
    float v[8];
    if (o < 25) {
        const float4 a = *(const float4*)&x[(size_t)n * FIN + o * 8];
        const float4 b = *(const float4*)&x[(size_t)n * FIN + o * 8 + 4];
        v[0]=a.x; v[1]=a.y; v[2]=a.z; v[3]=a.w; v[4]=b.x; v[5]=b.y; v[6]=b.z; v[7]=b.w;
    } else {
        #pragma unroll
        for (int j = 0; j < 8; ++j) v[j] = 0.f;
    }
    bf16x8 h, l;
    #pragma unroll
    for (int j = 0; j < 8; ++j) {
        const ushort hh = bf16rn(v[j]);
        h[j] = (short)hh;
        l[j] = (short)bf16rn(v[j] - __uint_as_float((uint)hh << 16));
    }
    const size_t addr = ((size_t)(n >> 4) * 7 + (o >> 2)) * 512
                      + (size_t)((o & 3) * 16 + (n & 15)) * 8;
    *(bf16x8*)&Xh[addr] = h;
    *(bf16x8*)&Xl[addr] = l;
}

// ---------------------------------------------------------------------------
// CSR build (verified R12)
// ---------------------------------------------------------------------------
__global__ void hist_k(const int* __restrict__ ei, int* __restrict__ deg)
{
    int e = blockIdx.x * blockDim.x + threadIdx.x;
    if (e < EE) atomicAdd(&deg[ei[EE + e]], 1);
}

__global__ __launch_bounds__(1024)
void scan_k(const int* __restrict__ deg, int* __restrict__ row_ptr,
            int* __restrict__ pos)
{
    __shared__ int part[1024];
    const int t = threadIdx.x;
    const int chunk = (NN + 1023) / 1024;
    const int i0 = t * chunk;
    const int i1 = min(i0 + chunk, NN);
    int s = 0;
    for (int i = i0; i < i1; ++i) s += deg[i];
    part[t] = s;
    __syncthreads();
    for (int off = 1; off < 1024; off <<= 1) {
        int v = (t >= off) ? part[t - off] : 0;
        __syncthreads();
        part[t] += v;
        __syncthreads();
    }
    int run = (t == 0) ? 0 : part[t - 1];
    for (int i = i0; i < i1; ++i) {
        const int d = deg[i];
        row_ptr[i] = run;
        pos[i] = run;
        run += d;
    }
    if (t == 0) row_ptr[NN] = part[1023];
}

__global__ void fill_k(const int* __restrict__ ei, int* __restrict__ pos,
                       int* __restrict__ eidx)
{
    int e = blockIdx.x * blockDim.x + threadIdx.x;
    if (e < EE) {
        const int slot = atomicAdd(&pos[ei[EE + e]], 1);
        eidx[slot] = ei[e];
    }
}

// one zero pass over deg (ints) + STATS/POOL (floats)
__global__ void zero2_k(int* __restrict__ deg, float* __restrict__ sp, int n1, int n2)
{
    int i = blockIdx.x * blockDim.x + threadIdx.x;
    if (i < n1) deg[i] = 0;
    else if (i < n1 + n2) sp[i - n1] = 0.f;
}

// ---------------------------------------------------------------------------
// gather (R14-proven): 4-deep edge loop + LDS-staged packed writes
// ---------------------------------------------------------------------------
__global__ __launch_bounds__(512)
void gather_pk(const float* __restrict__ base, const float* __restrict__ T1,
               const int* __restrict__ row_ptr, const int* __restrict__ eidx,
               ushort* __restrict__ Xh, ushort* __restrict__ Xl)
{
    __shared__ ushort lds_h[16][136];
    __shared__ ushort lds_l[16][136];
    const int t   = threadIdx.x;
    const int grp = t >> 5;
    const int ln  = t & 31;
    const int n   = blockIdx.x * 16 + grp;

    const float4 r = edge_gather(base, T1, eidx, n, ln, row_ptr[n], row_ptr[n + 1]);
    float v[4];
    v[0] = fmaxf(r.x, 0.f); v[1] = fmaxf(r.y, 0.f);
    v[2] = fmaxf(r.z, 0.f); v[3] = fmaxf(r.w, 0.f);
    ushort4 h4, l4;
    {
        ushort hh; float hf;
        hh = bf16rn(v[0]); hf = __uint_as_float((uint)hh << 16); h4.x = hh; l4.x = bf16rn(v[0] - hf);
        hh = bf16rn(v[1]); hf = __uint_as_float((uint)hh << 16); h4.y = hh; l4.y = bf16rn(v[1] - hf);
        hh = bf16rn(v[2]); hf = __uint_as_float((uint)hh << 16); h4.z = hh; l4.z = bf16rn(v[2] - hf);
        hh = bf16rn(v[3]); hf = __uint_as_float((uint)hh << 16); h4.w = hh; l4.w = bf16rn(v[3] - hf);
    }
    *(ushort4*)&lds_h[grp][ln * 4] = h4;
    *(ushort4*)&lds_l[grp][ln * 4] = l4;
    __syncthreads();

    const int nl = t & 15;
    const int o  = (t >> 4) & 15;
    const size_t addr = ((size_t)blockIdx.x * 4 + (o >> 2)) * 512
                      + (size_t)((o & 3) * 16 + nl) * 8;
    if (t < 256) {
        *(uint4*)&Xh[addr] = *(const uint4*)&lds_h[nl][o * 8];
    } else {
        *(uint4*)&Xl[addr] = *(const uint4*)&lds_l[nl][o * 8];
    }
}

// ---------------------------------------------------------------------------
// layer-5 gather FUSED with BN-stats + pooling (R15-measured win):
// 512 thr, 16 nodes, 1 pass; 3-way parallel reduction (sum/sumsq/pool).
// ---------------------------------------------------------------------------
__global__ __launch_bounds__(512)
void gather_bn(const float* __restrict__ base, const float* __restrict__ T1,
               const int* __restrict__ row_ptr, const int* __restrict__ eidx,
               const int* __restrict__ batch,
               float* __restrict__ stats, float* __restrict__ pool)
{
    __shared__ float vals[16][132];
    __shared__ int bg[16];
    const int t   = threadIdx.x;
    const int grp = t >> 5;
    const int ln  = t & 31;
    const int n0  = blockIdx.x * 16;
    const int n   = n0 + grp;

    const float4 r = edge_gather(base, T1, eidx, n, ln, row_ptr[n], row_ptr[n + 1]);
    vals[grp][ln * 4 + 0] = r.x;
    vals[grp][ln * 4 + 1] = r.y;
    vals[grp][ln * 4 + 2] = r.z;
    vals[grp][ln * 4 + 3] = r.w;
    if (t < 16) bg[t] = batch[n0 + t];
    __syncthreads();

    if (t < 128) {
        float s = 0.f;
        #pragma unroll
        for (int rr = 0; rr < 16; ++rr) s += vals[rr][t];
        atomicAdd(&stats[t], s);
    } else if (t < 256) {
        const int f = t - 128;
        float q = 0.f;
        #pragma unroll
        for (int rr = 0; rr < 16; ++rr) { const float v = vals[rr][f]; q += v * v; }
        atomicAdd(&stats[128 + f], q);
    } else if (t < 384) {
        const int f = t - 256;
        float acc = 0.f;
        int curg = bg[0];
        #pragma unroll
        for (int rr = 0; rr < 16; ++rr) {
            const int g = bg[rr];
            if (g != curg) {
                atomicAdd(&pool[(size_t)curg * HH + f], acc);
                acc = 0.f; curg = g;
            }
            acc += vals[rr][f];
        }
        atomicAdd(&pool[(size_t)curg * HH + f], acc);
    }
}

// BN affine on pooled means + linear head (verified R12)
__global__ __launch_bounds__(128)
void finalize(const float* __restrict__ stats, const float* __restrict__ pool,
              const int* __restrict__ batch,
              const float* __restrict__ gamma, const float* __restrict__ beta,
              const float* __restrict__ lin_w, const float* __restrict__ lin_b,
              float* __restrict__ out)
{
    const int g = blockIdx.x, f = threadIdx.x;
    __shared__ int seg[2];
    if (f < 2) {
        const int target = g + f;
        int lo = 0, hi = NN;
        while (lo < hi) {
            const int mid = (lo + hi) >> 1;
            if (batch[mid] < target) lo = mid + 1; else hi = mid;
        }
        seg[f] = lo;
    }
    __syncthreads();
    const float c   = (float)(seg[1] - seg[0]);
    const float mu  = stats[f] * (1.0f / NN);
    const float var = stats[128 + f] * (1.0f / NN) - mu * mu;
    const float scale = gamma[f] * rsqrtf(var + BN_EPS);
    const float pm = pool[(size_t)g * HH + f] / fmaxf(c, 1.0f);
    __shared__ float sh[128];
    sh[f] = (pm - mu) * scale + beta[f];
    __syncthreads();
    if (f < CC) {
        float s = lin_b[f];
        #pragma unroll 8
        for (int k = 0; k < HH; ++k) s += sh[k] * lin_w[f * HH + k];
        out[(size_t)g * CC + f] = s;
    }
}

extern "C" void kernel_launch(void* const* d_in, const int* in_sizes, int n_in,
                              void* d_out, int out_size, void* d_ws, size_t ws_size,
                              hipStream_t stream)
{
    const float* x       = (const float*)d_in[0];
    const int*   ei      = (const int*)d_in[1];
    const int*   batch   = (const int*)d_in[2];
    const float* w1_rel  = (const float*)d_in[3];
    const float* w1_root = (const float*)d_in[4];
    const float* b1      = (const float*)d_in[5];
    const float* w2_rel  = (const float*)d_in[6];
    const float* w2_root = (const float*)d_in[7];
    const float* b2      = (const float*)d_in[8];
    const float* w3_rel  = (const float*)d_in[9];
    const float* w3_root = (const float*)d_in[10];
    const float* b3      = (const float*)d_in[11];
    const float* w4_rel  = (const float*)d_in[12];
    const float* w4_root = (const float*)d_in[13];
    const float* b4      = (const float*)d_in[14];
    const float* w5_rel  = (const float*)d_in[15];   // [128, 512]
    const float* w5_root = (const float*)d_in[16];   // [128, 512]
    const float* b5      = (const float*)d_in[17];
    const float* gamma   = (const float*)d_in[18];
    const float* beta    = (const float*)d_in[19];
    const float* lin_w   = (const float*)d_in[20];
    const float* lin_b   = (const float*)d_in[21];
    float* out = (float*)d_out;

    const size_t NH = (size_t)NN * HH;   // 2,560,000
    float*  XR  = (float*)d_ws;
    float*  T1  = XR + NH;
    ushort* X1h = (ushort*)(T1 + NH);
    ushort* X1l = X1h + NH;
    ushort* X2h = X1l + NH;
    ushort* X2l = X2h + NH;
    ushort* X3h = X2l + NH;
    ushort* X3l = X3h + NH;
    ushort* X4h = X3l + NH;
    ushort* X4l = X4h + NH;
    const int K1P = 224;
    ushort* W1h = X4l + NH;
    ushort* W1l = W1h + 256 * K1P;
    ushort* W2h = W1l + 256 * K1P;
    ushort* W2l = W2h + 256 * 128;
    ushort* W3h = W2l + 256 * 128;
    ushort* W3l = W3h + 256 * 128;
    ushort* W4h = W3l + 256 * 128;
    ushort* W4l = W4h + 256 * 128;
    ushort* W5h = W4l + 256 * 128;
    ushort* W5l = W5h + 256 * 512;
    float*  STATS = (float*)(W5l + 256 * 512);   // 256
    float*  POOL  = STATS + 256;                 // GG*HH
    int* row_ptr = (int*)(POOL + (size_t)GG * HH);
    int* pos     = row_ptr + (NN + 1);
    int* deg     = pos + NN;
    int* eidx    = deg + NN;
    const size_t need = (size_t)(eidx + EE) - (size_t)d_ws;
    if (ws_size < need) return;

    // packed layer-1 input aliases X2h..X3l (dead once L1 GEMM completes)
    ushort* XPh = X2h;
    ushort* XPl = X2h + (size_t)NN * K1P;

    const dim3 blk(256);
    const int ggw   = NN / RPB;             // 250 blocks x 512 thr
    const int gedge = (EE + 255) / 256;
    const int ggpk  = NN / 16;              // 1250 blocks

    // single zero pass: deg (ints) + STATS/POOL (floats)
    const int nz = NN + 256 + GG * HH;
    zero2_k<<<(nz + 255) / 256, blk, 0, stream>>>(deg, STATS, NN, 256 + GG * HH);

    // CSR build
    hist_k<<<gedge, blk, 0, stream>>>(ei, deg);
    scan_k<<<1, dim3(1024), 0, stream>>>(deg, row_ptr, pos);
    fill_k<<<gedge, blk, 0, stream>>>(ei, pos, eidx);

    // all weight splits in one dispatch + layer-1 input pack
    split_all<<<1120, blk, 0, stream>>>(w1_root, w1_rel, w2_root, w2_rel,
                                        w3_root, w3_rel, w4_root, w4_rel,
                                        w5_root, w5_rel,
                                        W1h, W1l, W2h, W2l, W3h, W3l,
                                        W4h, W4l, W5h, W5l);
    pack_x<<<ggpk, dim3(448), 0, stream>>>(x, XPh, XPl);

    // layer 1 (K=224 packed)
    gemm_pk<7><<<ggw, dim3(512), 0, stream>>>(XPh, XPl, W1h, W1l, b1, XR, T1);
    gather_pk<<<ggpk, dim3(512), 0, stream>>>(XR, T1, row_ptr, eidx, X1h, X1l);
    // layers 2-4 (K=128 packed)
    gemm_pk<4><<<ggw, dim3(512), 0, stream>>>(X1h, X1l, W2h, W2l, b2, XR, T1);
    gather_pk<<<ggpk, dim3(512), 0, stream>>>(XR, T1, row_ptr, eidx, X2h, X2l);
    gemm_pk<4><<<ggw, dim3(512), 0, stream>>>(X2h, X2l, W3h, W3l, b3, XR, T1);
    gather_pk<<<ggpk, dim3(512), 0, stream>>>(XR, T1, row_ptr, eidx, X3h, X3l);
    gemm_pk<4><<<ggw, dim3(512), 0, stream>>>(X3h, X3l, W4h, W4l, b4, XR, T1);
    gather_pk<<<ggpk, dim3(512), 0, stream>>>(XR, T1, row_ptr, eidx, X4h, X4l);
    // layer 5: packed concat GEMM, then fused gather+BN+pool (X5 never stored)
    gemm_pk4<<<ggw, dim3(512), 0, stream>>>(X1h, X1l, X2h, X2l, X3h, X3l, X4h, X4l,
                                            W5h, W5l, b5, XR, T1);
    gather_bn<<<ggpk, dim3(512), 0, stream>>>(XR, T1, row_ptr, eidx, batch, STATS, POOL);

    // epilogue
    finalize<<<GG, dim3(128), 0, stream>>>(STATS, POOL, batch, gamma, beta, lin_w, lin_b, out);
}

// Round 17
// 286.433 us; speedup vs baseline: 1.1529x; 1.1210x over previous
//
#include <hip/hip_runtime.h>

#define NN 20000
#define EE 320000
#define FIN 200
#define HH 128
#define CC 10
#define GG 100
#define BN_EPS 1e-5f
#define RPB 80          // rows per gemm block; 250 blocks x 80 = 20000

typedef __attribute__((ext_vector_type(8))) short bf16x8;
typedef __attribute__((ext_vector_type(4))) float f32x4;

__device__ __forceinline__ ushort bf16rn(float x) {
    uint u = __float_as_uint(x);
    u += 0x7FFFu + ((u >> 16) & 1u);
    return (ushort)(u >> 16);
}
__device__ __forceinline__ float bf2f(ushort u) {
    return __uint_as_float((uint)u << 16);
}

// 4-deep-unrolled edge aggregation over bf16 T1 rows (256B each).
// Gathers are FETCH-bound (R16: 47us = 58.7MB / 1.31 TB/s random-row
// service rate); halving row bytes halves the dominant term.
__device__ __forceinline__
float4 edge_gather(const float* __restrict__ base, const ushort* __restrict__ T1,
                   const int* __restrict__ eidx, int n, int ln, int e0, int e1)
{
    float4 a0 = *(const float4*)&base[(size_t)n * HH + ln * 4];
    float4 a1 = {0,0,0,0}, a2 = {0,0,0,0}, a3 = {0,0,0,0};
    int e = e0;
    for (; e + 4 <= e1; e += 4) {
        const int s0 = eidx[e], s1 = eidx[e+1], s2 = eidx[e+2], s3 = eidx[e+3];
        const ushort4 u0 = *(const ushort4*)&T1[(size_t)s0 * HH + ln * 4];
        const ushort4 u1 = *(const ushort4*)&T1[(size_t)s1 * HH + ln * 4];
        const ushort4 u2 = *(const ushort4*)&T1[(size_t)s2 * HH + ln * 4];
        const ushort4 u3 = *(const ushort4*)&T1[(size_t)s3 * HH + ln * 4];
        a0.x += bf2f(u0.x); a0.y += bf2f(u0.y); a0.z += bf2f(u0.z); a0.w += bf2f(u0.w);
        a1.x += bf2f(u1.x); a1.y += bf2f(u1.y); a1.z += bf2f(u1.z); a1.w += bf2f(u1.w);
        a2.x += bf2f(u2.x); a2.y += bf2f(u2.y); a2.z += bf2f(u2.z); a2.w += bf2f(u2.w);
        a3.x += bf2f(u3.x); a3.y += bf2f(u3.y); a3.z += bf2f(u3.z); a3.w += bf2f(u3.w);
    }
    for (; e < e1; ++e) {
        const int s = eidx[e];
        const ushort4 u = *(const ushort4*)&T1[(size_t)s * HH + ln * 4];
        a0.x += bf2f(u.x); a0.y += bf2f(u.y); a0.z += bf2f(u.z); a0.w += bf2f(u.w);
    }
    float4 r;
    r.x = (a0.x + a1.x) + (a2.x + a3.x);
    r.y = (a0.y + a1.y) + (a2.y + a3.y);
    r.z = (a0.z + a1.z) + (a2.z + a3.z);
    r.w = (a0.w + a1.w) + (a2.w + a3.w);
    return r;
}

// Fragment-major packing (verified R11/R12):
// elem (r,k) -> ((r>>4)*(K/32) + (k>>5))*512 + (((k>>3)&3)*16 + (r&15))*8 + (k&7)

// ---------------------------------------------------------------------------
// Packed W-in-registers GEMM (R12 core): Croot fp32 (+bias), Crel bf16 (T1)
// ---------------------------------------------------------------------------
template<int KSTEPS>
__global__ __launch_bounds__(512)
void gemm_pk(const ushort* __restrict__ Aph, const ushort* __restrict__ Apl,
             const ushort* __restrict__ Wph, const ushort* __restrict__ Wpl,
             const float* __restrict__ bias,
             float* __restrict__ Croot, ushort* __restrict__ Crel)
{
    const int wid  = threadIdx.x >> 6;
    const int lane = threadIdx.x & 63;
    const int l15  = lane & 15;
    const int matsel = wid >> 2;
    const int ncol = (wid & 3) * 32;
    const int wrg0 = matsel * 8 + (ncol >> 4);
    const int rowb = (lane >> 4) * 4;
    const int rbase0 = blockIdx.x * RPB;

    bf16x8 wh[2][KSTEPS], wl[2][KSTEPS];
    #pragma unroll
    for (int nf = 0; nf < 2; ++nf) {
        const size_t wbase = (size_t)(wrg0 + nf) * KSTEPS * 512;
        #pragma unroll
        for (int ks = 0; ks < KSTEPS; ++ks) {
            wh[nf][ks] = *(const bf16x8*)&Wph[wbase + (size_t)(ks * 64 + lane) * 8];
            wl[nf][ks] = *(const bf16x8*)&Wpl[wbase + (size_t)(ks * 64 + lane) * 8];
        }
    }
    float bv[2] = {0.f, 0.f};
    if (matsel == 0 && bias) { bv[0] = bias[ncol + l15]; bv[1] = bias[ncol + 16 + l15]; }

    for (int ch = 0; ch < RPB; ch += 16) {
        const size_t abase = (size_t)((rbase0 + ch) >> 4) * KSTEPS * 512;
        f32x4 acc[2] = {};
        #pragma unroll
        for (int ks = 0; ks < KSTEPS; ++ks) {
            const bf16x8 ah = *(const bf16x8*)&Aph[abase + (size_t)(ks * 64 + lane) * 8];
            const bf16x8 al = *(const bf16x8*)&Apl[abase + (size_t)(ks * 64 + lane) * 8];
            #pragma unroll
            for (int nf = 0; nf < 2; ++nf) {
                acc[nf] = __builtin_amdgcn_mfma_f32_16x16x32_bf16(ah, wh[nf][ks], acc[nf], 0, 0, 0);
                acc[nf] = __builtin_amdgcn_mfma_f32_16x16x32_bf16(al, wh[nf][ks], acc[nf], 0, 0, 0);
                acc[nf] = __builtin_amdgcn_mfma_f32_16x16x32_bf16(ah, wl[nf][ks], acc[nf], 0, 0, 0);
            }
        }
        #pragma unroll
        for (int nf = 0; nf < 2; ++nf) {
            const int col = ncol + nf * 16 + l15;   // LOCAL column (0..127)
            #pragma unroll
            for (int j = 0; j < 4; ++j) {
                const int row = rbase0 + ch + rowb + j;
                const float v = acc[nf][j] + bv[nf];
                if (matsel == 0) Croot[(size_t)row * HH + col] = v;
                else             Crel[(size_t)row * HH + col]  = bf16rn(v);
            }
        }
    }
}

// ---------------------------------------------------------------------------
// Layer-5 packed concat-GEMM (R12 core), T1 output bf16
// ---------------------------------------------------------------------------
__global__ __launch_bounds__(512)
void gemm_pk4(const ushort* __restrict__ X1h, const ushort* __restrict__ X1l,
              const ushort* __restrict__ X2h, const ushort* __restrict__ X2l,
              const ushort* __restrict__ X3h, const ushort* __restrict__ X3l,
              const ushort* __restrict__ X4h, const ushort* __restrict__ X4l,
              const ushort* __restrict__ Wph, const ushort* __restrict__ Wpl,
              const float* __restrict__ bias,
              float* __restrict__ Croot, ushort* __restrict__ Crel)
{
    const int wid  = threadIdx.x >> 6;
    const int lane = threadIdx.x & 63;
    const int l15  = lane & 15;
    const int matsel = wid >> 2;
    const int ncol = (wid & 3) * 32;
    const int wrg0 = matsel * 8 + (ncol >> 4);
    const int rowb = (lane >> 4) * 4;
    const int rbase0 = blockIdx.x * RPB;
    const ushort* const Ahs[4] = {X1h, X2h, X3h, X4h};
    const ushort* const Als[4] = {X1l, X2l, X3l, X4l};

    f32x4 acc[5][2] = {};
    #pragma unroll
    for (int src = 0; src < 4; ++src) {
        const ushort* __restrict__ Ah_ = Ahs[src];
        const ushort* __restrict__ Al_ = Als[src];
        bf16x8 wh[2][4], wl[2][4];
        #pragma unroll
        for (int nf = 0; nf < 2; ++nf) {
            const size_t wbase = ((size_t)(wrg0 + nf) * 16 + src * 4) * 512;
            #pragma unroll
            for (int ks = 0; ks < 4; ++ks) {
                wh[nf][ks] = *(const bf16x8*)&Wph[wbase + (size_t)(ks * 64 + lane) * 8];
                wl[nf][ks] = *(const bf16x8*)&Wpl[wbase + (size_t)(ks * 64 + lane) * 8];
            }
        }
        #pragma unroll
        for (int ch = 0; ch < 5; ++ch) {
            const size_t abase = (size_t)((rbase0 + ch * 16) >> 4) * 4 * 512;
            #pragma unroll
            for (int ks = 0; ks < 4; ++ks) {
                const bf16x8 ah = *(const bf16x8*)&Ah_[abase + (size_t)(ks * 64 + lane) * 8];
                const bf16x8 al = *(const bf16x8*)&Al_[abase + (size_t)(ks * 64 + lane) * 8];
                #pragma unroll
                for (int nf = 0; nf < 2; ++nf) {
                    acc[ch][nf] = __builtin_amdgcn_mfma_f32_16x16x32_bf16(ah, wh[nf][ks], acc[ch][nf], 0, 0, 0);
                    acc[ch][nf] = __builtin_amdgcn_mfma_f32_16x16x32_bf16(al, wh[nf][ks], acc[ch][nf], 0, 0, 0);
                    acc[ch][nf] = __builtin_amdgcn_mfma_f32_16x16x32_bf16(ah, wl[nf][ks], acc[ch][nf], 0, 0, 0);
                }
            }
        }
    }
    float bv[2] = {0.f, 0.f};
    if (matsel == 0 && bias) { bv[0] = bias[ncol + l15]; bv[1] = bias[ncol + 16 + l15]; }
    #pragma unroll
    for (int ch = 0; ch < 5; ++ch) {
        #pragma unroll
        for (int nf = 0; nf < 2; ++nf) {
            const int col = ncol + nf * 16 + l15;
            #pragma unroll
            for (int j = 0; j < 4; ++j) {
                const int row = rbase0 + ch * 16 + rowb + j;
                const float v = acc[ch][nf][j] + bv[nf];
                if (matsel == 0) Croot[(size_t)row * HH + col] = v;
                else             Crel[(size_t)row * HH + col]  = bf16rn(v);
            }
        }
    }
}

// ---------------------------------------------------------------------------
// all 5 weight splits in ONE dispatch (verified R14)
// ---------------------------------------------------------------------------
__global__ __launch_bounds__(256)
void split_all(const float* __restrict__ r1, const float* __restrict__ e1,
               const float* __restrict__ r2, const float* __restrict__ e2,
               const float* __restrict__ r3, const float* __restrict__ e3,
               const float* __restrict__ r4, const float* __restrict__ e4,
               const float* __restrict__ r5, const float* __restrict__ e5,
               ushort* __restrict__ W1h, ushort* __restrict__ W1l,
               ushort* __restrict__ W2h, ushort* __restrict__ W2l,
               ushort* __restrict__ W3h, ushort* __restrict__ W3l,
               ushort* __restrict__ W4h, ushort* __restrict__ W4l,
               ushort* __restrict__ W5h, ushort* __restrict__ W5l)
{
    const int b = blockIdx.x;
    const float *Wroot, *Wrel; int K, Kp, base; ushort *Wh, *Wl;
    if (b < 224)      { Wroot = r1; Wrel = e1; K = FIN; Kp = 224; Wh = W1h; Wl = W1l; base = 0; }
    else if (b < 352) { Wroot = r2; Wrel = e2; K = 128; Kp = 128; Wh = W2h; Wl = W2l; base = 224; }
    else if (b < 480) { Wroot = r3; Wrel = e3; K = 128; Kp = 128; Wh = W3h; Wl = W3l; base = 352; }
    else if (b < 608) { Wroot = r4; Wrel = e4; K = 128; Kp = 128; Wh = W4h; Wl = W4l; base = 480; }
    else              { Wroot = r5; Wrel = e5; K = 512; Kp = 512; Wh = W5h; Wl = W5l; base = 608; }
    const int i = (b - base) * 256 + threadIdx.x;
    const int row = i / Kp, col = i - row * Kp;
    float v = 0.f;
    if (col < K) v = (row < 128) ? Wroot[row * K + col] : Wrel[(row - 128) * K + col];
    const ushort h = bf16rn(v);
    const float hf = __uint_as_float((uint)h << 16);
    const int ksteps = Kp >> 5;
    const size_t addr = ((size_t)(row >> 4) * ksteps + (col >> 5)) * 512
                      + (size_t)(((col >> 3) & 3) * 16 + (row & 15)) * 8 + (col & 7);
    Wh[addr] = h;
    Wl[addr] = bf16rn(v - hf);
}

// ---------------------------------------------------------------------------
// pack layer-1 input (verified R12)
// ---------------------------------------------------------------------------
__global__ __launch_bounds__(448)
void pack_x(const float* __restrict__ x, ushort* __restrict__ Xh, ushort* __restrict__ Xl)
{
    const int t = threadIdx.x;
    const int n = blockIdx.x * 16 + (t & 15);
    const int o = t >> 4;                   // k-octet 0..27
    float v[8];
    if (o < 25) {
        const float4 a = *(const float4*)&x[(size_t)n * FIN + o * 8];
        const float4 b = *(const float4*)&x[(size_t)n * FIN + o * 8 + 4];
        v[0]=a.x; v[1]=a.y; v[2]=a.z; v[3]=a.w; v[4]=b.x; v[5]=b.y; v[6]=b.z; v[7]=b.w;
    } else {
        #pragma unroll
        for (int j = 0; j < 8; ++j) v[j] = 0.f;
    }
    bf16x8 h, l;
    #pragma unroll
    for (int j = 0; j < 8; ++j) {
        const ushort hh = bf16rn(v[j]);
        h[j] = (short)hh;
        l[j] = (short)bf16rn(v[j] - __uint_as_float((uint)hh << 16));
    }
    const size_t addr = ((size_t)(n >> 4) * 7 + (o >> 2)) * 512
                      + (size_t)((o & 3) * 16 + (n & 15)) * 8;
    *(bf16x8*)&Xh[addr] = h;
    *(bf16x8*)&Xl[addr] = l;
}

// ---------------------------------------------------------------------------
// CSR build (verified R12)
// ---------------------------------------------------------------------------
__global__ void hist_k(const int* __restrict__ ei, int* __restrict__ deg)
{
    int e = blockIdx.x * blockDim.x + threadIdx.x;
    if (e < EE) atomicAdd(&deg[ei[EE + e]], 1);
}

__global__ __launch_bounds__(1024)
void scan_k(const int* __restrict__ deg, int* __restrict__ row_ptr,
            int* __restrict__ pos)
{
    __shared__ int part[1024];
    const int t = threadIdx.x;
    const int chunk = (NN + 1023) / 1024;
    const int i0 = t * chunk;
    const int i1 = min(i0 + chunk, NN);
    int s = 0;
    for (int i = i0; i < i1; ++i) s += deg[i];
    part[t] = s;
    __syncthreads();
    for (int off = 1; off < 1024; off <<= 1) {
        int v = (t >= off) ? part[t - off] : 0;
        __syncthreads();
        part[t] += v;
        __syncthreads();
    }
    int run = (t == 0) ? 0 : part[t - 1];
    for (int i = i0; i < i1; ++i) {
        const int d = deg[i];
        row_ptr[i] = run;
        pos[i] = run;
        run += d;
    }
    if (t == 0) row_ptr[NN] = part[1023];
}

__global__ void fill_k(const int* __restrict__ ei, int* __restrict__ pos,
                       int* __restrict__ eidx)
{
    int e = blockIdx.x * blockDim.x + threadIdx.x;
    if (e < EE) {
        const int slot = atomicAdd(&pos[ei[EE + e]], 1);
        eidx[slot] = ei[e];
    }
}

// one zero pass over deg (ints) + STATS/POOL (floats)
__global__ void zero2_k(int* __restrict__ deg, float* __restrict__ sp, int n1, int n2)
{
    int i = blockIdx.x * blockDim.x + threadIdx.x;
    if (i < n1) deg[i] = 0;
    else if (i < n1 + n2) sp[i - n1] = 0.f;
}

// ---------------------------------------------------------------------------
// gather (R14 structure, bf16 T1): 4-deep edge loop + LDS-staged packed writes
// ---------------------------------------------------------------------------
__global__ __launch_bounds__(512)
void gather_pk(const float* __restrict__ base, const ushort* __restrict__ T1,
               const int* __restrict__ row_ptr, const int* __restrict__ eidx,
               ushort* __restrict__ Xh, ushort* __restrict__ Xl)
{
    __shared__ ushort lds_h[16][136];
    __shared__ ushort lds_l[16][136];
    const int t   = threadIdx.x;
    const int grp = t >> 5;
    const int ln  = t & 31;
    const int n   = blockIdx.x * 16 + grp;

    const float4 r = edge_gather(base, T1, eidx, n, ln, row_ptr[n], row_ptr[n + 1]);
    float v[4];
    v[0] = fmaxf(r.x, 0.f); v[1] = fmaxf(r.y, 0.f);
    v[2] = fmaxf(r.z, 0.f); v[3] = fmaxf(r.w, 0.f);
    ushort4 h4, l4;
    {
        ushort hh; float hf;
        hh = bf16rn(v[0]); hf = __uint_as_float((uint)hh << 16); h4.x = hh; l4.x = bf16rn(v[0] - hf);
        hh = bf16rn(v[1]); hf = __uint_as_float((uint)hh << 16); h4.y = hh; l4.y = bf16rn(v[1] - hf);
        hh = bf16rn(v[2]); hf = __uint_as_float((uint)hh << 16); h4.z = hh; l4.z = bf16rn(v[2] - hf);
        hh = bf16rn(v[3]); hf = __uint_as_float((uint)hh << 16); h4.w = hh; l4.w = bf16rn(v[3] - hf);
    }
    *(ushort4*)&lds_h[grp][ln * 4] = h4;
    *(ushort4*)&lds_l[grp][ln * 4] = l4;
    __syncthreads();

    const int nl = t & 15;
    const int o  = (t >> 4) & 15;
    const size_t addr = ((size_t)blockIdx.x * 4 + (o >> 2)) * 512
                      + (size_t)((o & 3) * 16 + nl) * 8;
    if (t < 256) {
        *(uint4*)&Xh[addr] = *(const uint4*)&lds_h[nl][o * 8];
    } else {
        *(uint4*)&Xl[addr] = *(const uint4*)&lds_l[nl][o * 8];
    }
}

// ---------------------------------------------------------------------------
// layer-5 gather FUSED with BN-stats + pooling (R15-measured win), bf16 T1
// ---------------------------------------------------------------------------
__global__ __launch_bounds__(512)
void gather_bn(const float* __restrict__ base, const ushort* __restrict__ T1,
               const int* __restrict__ row_ptr, const int* __restrict__ eidx,
               const int* __restrict__ batch,
               float* __restrict__ stats, float* __restrict__ pool)
{
    __shared__ float vals[16][132];
    __shared__ int bg[16];
    const int t   = threadIdx.x;
    const int grp = t >> 5;
    const int ln  = t & 31;
    const int n0  = blockIdx.x * 16;
    const int n   = n0 + grp;

    const float4 r = edge_gather(base, T1, eidx, n, ln, row_ptr[n], row_ptr[n + 1]);
    vals[grp][ln * 4 + 0] = r.x;
    vals[grp][ln * 4 + 1] = r.y;
    vals[grp][ln * 4 + 2] = r.z;
    vals[grp][ln * 4 + 3] = r.w;
    if (t < 16) bg[t] = batch[n0 + t];
    __syncthreads();

    if (t < 128) {
        float s = 0.f;
        #pragma unroll
        for (int rr = 0; rr < 16; ++rr) s += vals[rr][t];
        atomicAdd(&stats[t], s);
    } else if (t < 256) {
        const int f = t - 128;
        float q = 0.f;
        #pragma unroll
        for (int rr = 0; rr < 16; ++rr) { const float v = vals[rr][f]; q += v * v; }
        atomicAdd(&stats[128 + f], q);
    } else if (t < 384) {
        const int f = t - 256;
        float acc = 0.f;
        int curg = bg[0];
        #pragma unroll
        for (int rr = 0; rr < 16; ++rr) {
            const int g = bg[rr];
            if (g != curg) {
                atomicAdd(&pool[(size_t)curg * HH + f], acc);
                acc = 0.f; curg = g;
            }
            acc += vals[rr][f];
        }
        atomicAdd(&pool[(size_t)curg * HH + f], acc);
    }
}

// BN affine on pooled means + linear head (verified R12)
__global__ __launch_bounds__(128)
void finalize(const float* __restrict__ stats, const float* __restrict__ pool,
              const int* __restrict__ batch,
              const float* __restrict__ gamma, const float* __restrict__ beta,
              const float* __restrict__ lin_w, const float* __restrict__ lin_b,
              float* __restrict__ out)
{
    const int g = blockIdx.x, f = threadIdx.x;
    __shared__ int seg[2];
    if (f < 2) {
        const int target = g + f;
        int lo = 0, hi = NN;
        while (lo < hi) {
            const int mid = (lo + hi) >> 1;
            if (batch[mid] < target) lo = mid + 1; else hi = mid;
        }
        seg[f] = lo;
    }
    __syncthreads();
    const float c   = (float)(seg[1] - seg[0]);
    const float mu  = stats[f] * (1.0f / NN);
    const float var = stats[128 + f] * (1.0f / NN) - mu * mu;
    const float scale = gamma[f] * rsqrtf(var + BN_EPS);
    const float pm = pool[(size_t)g * HH + f] / fmaxf(c, 1.0f);
    __shared__ float sh[128];
    sh[f] = (pm - mu) * scale + beta[f];
    __syncthreads();
    if (f < CC) {
        float s = lin_b[f];
        #pragma unroll 8
        for (int k = 0; k < HH; ++k) s += sh[k] * lin_w[f * HH + k];
        out[(size_t)g * CC + f] = s;
    }
}

extern "C" void kernel_launch(void* const* d_in, const int* in_sizes, int n_in,
                              void* d_out, int out_size, void* d_ws, size_t ws_size,
                              hipStream_t stream)
{
    const float* x       = (const float*)d_in[0];
    const int*   ei      = (const int*)d_in[1];
    const int*   batch   = (const int*)d_in[2];
    const float* w1_rel  = (const float*)d_in[3];
    const float* w1_root = (const float*)d_in[4];
    const float* b1      = (const float*)d_in[5];
    const float* w2_rel  = (const float*)d_in[6];
    const float* w2_root = (const float*)d_in[7];
    const float* b2      = (const float*)d_in[8];
    const float* w3_rel  = (const float*)d_in[9];
    const float* w3_root = (const float*)d_in[10];
    const float* b3      = (const float*)d_in[11];
    const float* w4_rel  = (const float*)d_in[12];
    const float* w4_root = (const float*)d_in[13];
    const float* b4      = (const float*)d_in[14];
    const float* w5_rel  = (const float*)d_in[15];   // [128, 512]
    const float* w5_root = (const float*)d_in[16];   // [128, 512]
    const float* b5      = (const float*)d_in[17];
    const float* gamma   = (const float*)d_in[18];
    const float* beta    = (const float*)d_in[19];
    const float* lin_w   = (const float*)d_in[20];
    const float* lin_b   = (const float*)d_in[21];
    float* out = (float*)d_out;

    const size_t NH = (size_t)NN * HH;   // 2,560,000
    float*  XR  = (float*)d_ws;
    float*  T1SPACE = XR + NH;           // NH floats reserved; bf16 T1 uses half
    ushort* T1  = (ushort*)T1SPACE;
    ushort* X1h = (ushort*)(T1SPACE + NH);
    ushort* X1l = X1h + NH;
    ushort* X2h = X1l + NH;
    ushort* X2l = X2h + NH;
    ushort* X3h = X2l + NH;
    ushort* X3l = X3h + NH;
    ushort* X4h = X3l + NH;
    ushort* X4l = X4h + NH;
    const int K1P = 224;
    ushort* W1h = X4l + NH;
    ushort* W1l = W1h + 256 * K1P;
    ushort* W2h = W1l + 256 * K1P;
    ushort* W2l = W2h + 256 * 128;
    ushort* W3h = W2l + 256 * 128;
    ushort* W3l = W3h + 256 * 128;
    ushort* W4h = W3l + 256 * 128;
    ushort* W4l = W4h + 256 * 128;
    ushort* W5h = W4l + 256 * 128;
    ushort* W5l = W5h + 256 * 512;
    float*  STATS = (float*)(W5l + 256 * 512);   // 256
    float*  POOL  = STATS + 256;                 // GG*HH
    int* row_ptr = (int*)(POOL + (size_t)GG * HH);
    int* pos     = row_ptr + (NN + 1);
    int* deg     = pos + NN;
    int* eidx    = deg + NN;
    const size_t need = (size_t)(eidx + EE) - (size_t)d_ws;
    if (ws_size < need) return;

    // packed layer-1 input aliases X2h..X3l (dead once L1 GEMM completes)
    ushort* XPh = X2h;
    ushort* XPl = X2h + (size_t)NN * K1P;

    const dim3 blk(256);
    const int ggw   = NN / RPB;             // 250 blocks x 512 thr
    const int gedge = (EE + 255) / 256;
    const int ggpk  = NN / 16;              // 1250 blocks

    // single zero pass: deg (ints) + STATS/POOL (floats)
    const int nz = NN + 256 + GG * HH;
    zero2_k<<<(nz + 255) / 256, blk, 0, stream>>>(deg, STATS, NN, 256 + GG * HH);

    // CSR build
    hist_k<<<gedge, blk, 0, stream>>>(ei, deg);
    scan_k<<<1, dim3(1024), 0, stream>>>(deg, row_ptr, pos);
    fill_k<<<gedge, blk, 0, stream>>>(ei, pos, eidx);

    // all weight splits in one dispatch + layer-1 input pack
    split_all<<<1120, blk, 0, stream>>>(w1_root, w1_rel, w2_root, w2_rel,
                                        w3_root, w3_rel, w4_root, w4_rel,
                                        w5_root, w5_rel,
                                        W1h, W1l, W2h, W2l, W3h, W3l,
                                        W4h, W4l, W5h, W5l);
    pack_x<<<ggpk, dim3(448), 0, stream>>>(x, XPh, XPl);

    // layer 1 (K=224 packed)
    gemm_pk<7><<<ggw, dim3(512), 0, stream>>>(XPh, XPl, W1h, W1l, b1, XR, T1);
    gather_pk<<<ggpk, dim3(512), 0, stream>>>(XR, T1, row_ptr, eidx, X1h, X1l);
    // layers 2-4 (K=128 packed)
    gemm_pk<4><<<ggw, dim3(512), 0, stream>>>(X1h, X1l, W2h, W2l, b2, XR, T1);
    gather_pk<<<ggpk, dim3(512), 0, stream>>>(XR, T1, row_ptr, eidx, X2h, X2l);
    gemm_pk<4><<<ggw, dim3(512), 0, stream>>>(X2h, X2l, W3h, W3l, b3, XR, T1);
    gather_pk<<<ggpk, dim3(512), 0, stream>>>(XR, T1, row_ptr, eidx, X3h, X3l);
    gemm_pk<4><<<ggw, dim3(512), 0, stream>>>(X3h, X3l, W4h, W4l, b4, XR, T1);
    gather_pk<<<ggpk, dim3(512), 0, stream>>>(XR, T1, row_ptr, eidx, X4h, X4l);
    // layer 5: packed concat GEMM, then fused gather+BN+pool (X5 never stored)
    gemm_pk4<<<ggw, dim3(512), 0, stream>>>(X1h, X1l, X2h, X2l, X3h, X3l, X4h, X4l,
                                            W5h, W5l, b5, XR, T1);
    gather_bn<<<ggpk, dim3(512), 0, stream>>>(XR, T1, row_ptr, eidx, batch, STATS, POOL);

    // epilogue
    finalize<<<GG, dim3(128), 0, stream>>>(STATS, POOL, batch, gamma, beta, lin_w, lin_b, out);
}

// Round 18
// 285.189 us; speedup vs baseline: 1.1579x; 1.0044x over previous
//
#include <hip/hip_runtime.h>

#define NN 20000
#define EE 320000
#define FIN 200
#define HH 128
#define CC 10
#define GG 100
#define BN_EPS 1e-5f
#define RPB 32          // rows per gemm block; 625 blocks x 32 = 20000 exact

typedef __attribute__((ext_vector_type(8))) short bf16x8;
typedef __attribute__((ext_vector_type(4))) float f32x4;

__device__ __forceinline__ ushort bf16rn(float x) {
    uint u = __float_as_uint(x);
    u += 0x7FFFu + ((u >> 16) & 1u);
    return (ushort)(u >> 16);
}
__device__ __forceinline__ float bf2f(ushort u) {
    return __uint_as_float((uint)u << 16);
}

// 4-deep edge aggregation over bf16 T1 rows, with software-pipelined index
// prefetch: next round's eidx loads issue BEFORE the wait on current row
// loads (gathers are request-rate bound per R17: FETCH halved, time -8%).
__device__ __forceinline__
float4 edge_gather(const float* __restrict__ base, const ushort* __restrict__ T1,
                   const int* __restrict__ eidx, int n, int ln, int e0, int e1)
{
    float4 a0 = *(const float4*)&base[(size_t)n * HH + ln * 4];
    float4 a1 = {0,0,0,0}, a2 = {0,0,0,0}, a3 = {0,0,0,0};
    int e = e0;
    int s0, s1, s2, s3;
    if (e + 4 <= e1) { s0 = eidx[e]; s1 = eidx[e+1]; s2 = eidx[e+2]; s3 = eidx[e+3]; }
    while (e + 4 <= e1) {
        const ushort4 u0 = *(const ushort4*)&T1[(size_t)s0 * HH + ln * 4];
        const ushort4 u1 = *(const ushort4*)&T1[(size_t)s1 * HH + ln * 4];
        const ushort4 u2 = *(const ushort4*)&T1[(size_t)s2 * HH + ln * 4];
        const ushort4 u3 = *(const ushort4*)&T1[(size_t)s3 * HH + ln * 4];
        e += 4;
        if (e + 4 <= e1) {      // prefetch next indices under row-load latency
            s0 = eidx[e]; s1 = eidx[e+1]; s2 = eidx[e+2]; s3 = eidx[e+3];
        }
        a0.x += bf2f(u0.x); a0.y += bf2f(u0.y); a0.z += bf2f(u0.z); a0.w += bf2f(u0.w);
        a1.x += bf2f(u1.x); a1.y += bf2f(u1.y); a1.z += bf2f(u1.z); a1.w += bf2f(u1.w);
        a2.x += bf2f(u2.x); a2.y += bf2f(u2.y); a2.z += bf2f(u2.z); a2.w += bf2f(u2.w);
        a3.x += bf2f(u3.x); a3.y += bf2f(u3.y); a3.z += bf2f(u3.z); a3.w += bf2f(u3.w);
    }
    for (; e < e1; ++e) {
        const int s = eidx[e];
        const ushort4 u = *(const ushort4*)&T1[(size_t)s * HH + ln * 4];
        a0.x += bf2f(u.x); a0.y += bf2f(u.y); a0.z += bf2f(u.z); a0.w += bf2f(u.w);
    }
    float4 r;
    r.x = (a0.x + a1.x) + (a2.x + a3.x);
    r.y = (a0.y + a1.y) + (a2.y + a3.y);
    r.z = (a0.z + a1.z) + (a2.z + a3.z);
    r.w = (a0.w + a1.w) + (a2.w + a3.w);
    return r;
}

// Fragment-major packing (verified R11/R12):
// elem (r,k) -> ((r>>4)*(K/32) + (k>>5))*512 + (((k>>3)&3)*16 + (r&15))*8 + (k&7)

// ---------------------------------------------------------------------------
// Packed W-in-registers GEMM (R12 core, RPB=32 -> 625 blocks for occupancy):
// Croot fp32 (+bias), Crel bf16 (T1)
// ---------------------------------------------------------------------------
template<int KSTEPS>
__global__ __launch_bounds__(512)
void gemm_pk(const ushort* __restrict__ Aph, const ushort* __restrict__ Apl,
             const ushort* __restrict__ Wph, const ushort* __restrict__ Wpl,
             const float* __restrict__ bias,
             float* __restrict__ Croot, ushort* __restrict__ Crel)
{
    const int wid  = threadIdx.x >> 6;
    const int lane = threadIdx.x & 63;
    const int l15  = lane & 15;
    const int matsel = wid >> 2;
    const int ncol = (wid & 3) * 32;
    const int wrg0 = matsel * 8 + (ncol >> 4);
    const int rowb = (lane >> 4) * 4;
    const int rbase0 = blockIdx.x * RPB;

    bf16x8 wh[2][KSTEPS], wl[2][KSTEPS];
    #pragma unroll
    for (int nf = 0; nf < 2; ++nf) {
        const size_t wbase = (size_t)(wrg0 + nf) * KSTEPS * 512;
        #pragma unroll
        for (int ks = 0; ks < KSTEPS; ++ks) {
            wh[nf][ks] = *(const bf16x8*)&Wph[wbase + (size_t)(ks * 64 + lane) * 8];
            wl[nf][ks] = *(const bf16x8*)&Wpl[wbase + (size_t)(ks * 64 + lane) * 8];
        }
    }
    float bv[2] = {0.f, 0.f};
    if (matsel == 0 && bias) { bv[0] = bias[ncol + l15]; bv[1] = bias[ncol + 16 + l15]; }

    #pragma unroll
    for (int ch = 0; ch < RPB; ch += 16) {
        const size_t abase = (size_t)((rbase0 + ch) >> 4) * KSTEPS * 512;
        f32x4 acc[2] = {};
        #pragma unroll
        for (int ks = 0; ks < KSTEPS; ++ks) {
            const bf16x8 ah = *(const bf16x8*)&Aph[abase + (size_t)(ks * 64 + lane) * 8];
            const bf16x8 al = *(const bf16x8*)&Apl[abase + (size_t)(ks * 64 + lane) * 8];
            #pragma unroll
            for (int nf = 0; nf < 2; ++nf) {
                acc[nf] = __builtin_amdgcn_mfma_f32_16x16x32_bf16(ah, wh[nf][ks], acc[nf], 0, 0, 0);
                acc[nf] = __builtin_amdgcn_mfma_f32_16x16x32_bf16(al, wh[nf][ks], acc[nf], 0, 0, 0);
                acc[nf] = __builtin_amdgcn_mfma_f32_16x16x32_bf16(ah, wl[nf][ks], acc[nf], 0, 0, 0);
            }
        }
        #pragma unroll
        for (int nf = 0; nf < 2; ++nf) {
            const int col = ncol + nf * 16 + l15;   // LOCAL column (0..127)
            #pragma unroll
            for (int j = 0; j < 4; ++j) {
                const int row = rbase0 + ch + rowb + j;
                const float v = acc[nf][j] + bv[nf];
                if (matsel == 0) Croot[(size_t)row * HH + col] = v;
                else             Crel[(size_t)row * HH + col]  = bf16rn(v);
            }
        }
    }
}

// ---------------------------------------------------------------------------
// Layer-5 packed concat-GEMM (RPB=32: 2 chunks, acc[2][2]), T1 output bf16
// ---------------------------------------------------------------------------
__global__ __launch_bounds__(512)
void gemm_pk4(const ushort* __restrict__ X1h, const ushort* __restrict__ X1l,
              const ushort* __restrict__ X2h, const ushort* __restrict__ X2l,
              const ushort* __restrict__ X3h, const ushort* __restrict__ X3l,
              const ushort* __restrict__ X4h, const ushort* __restrict__ X4l,
              const ushort* __restrict__ Wph, const ushort* __restrict__ Wpl,
              const float* __restrict__ bias,
              float* __restrict__ Croot, ushort* __restrict__ Crel)
{
    const int wid  = threadIdx.x >> 6;
    const int lane = threadIdx.x & 63;
    const int l15  = lane & 15;
    const int matsel = wid >> 2;
    const int ncol = (wid & 3) * 32;
    const int wrg0 = matsel * 8 + (ncol >> 4);
    const int rowb = (lane >> 4) * 4;
    const int rbase0 = blockIdx.x * RPB;
    const ushort* const Ahs[4] = {X1h, X2h, X3h, X4h};
    const ushort* const Als[4] = {X1l, X2l, X3l, X4l};

    f32x4 acc[2][2] = {};
    #pragma unroll
    for (int src = 0; src < 4; ++src) {
        const ushort* __restrict__ Ah_ = Ahs[src];
        const ushort* __restrict__ Al_ = Als[src];
        bf16x8 wh[2][4], wl[2][4];
        #pragma unroll
        for (int nf = 0; nf < 2; ++nf) {
            const size_t wbase = ((size_t)(wrg0 + nf) * 16 + src * 4) * 512;
            #pragma unroll
            for (int ks = 0; ks < 4; ++ks) {
                wh[nf][ks] = *(const bf16x8*)&Wph[wbase + (size_t)(ks * 64 + lane) * 8];
                wl[nf][ks] = *(const bf16x8*)&Wpl[wbase + (size_t)(ks * 64 + lane) * 8];
            }
        }
        #pragma unroll
        for (int ch = 0; ch < 2; ++ch) {
            const size_t abase = (size_t)((rbase0 + ch * 16) >> 4) * 4 * 512;
            #pragma unroll
            for (int ks = 0; ks < 4; ++ks) {
                const bf16x8 ah = *(const bf16x8*)&Ah_[abase + (size_t)(ks * 64 + lane) * 8];
                const bf16x8 al = *(const bf16x8*)&Al_[abase + (size_t)(ks * 64 + lane) * 8];
                #pragma unroll
                for (int nf = 0; nf < 2; ++nf) {
                    acc[ch][nf] = __builtin_amdgcn_mfma_f32_16x16x32_bf16(ah, wh[nf][ks], acc[ch][nf], 0, 0, 0);
                    acc[ch][nf] = __builtin_amdgcn_mfma_f32_16x16x32_bf16(al, wh[nf][ks], acc[ch][nf], 0, 0, 0);
                    acc[ch][nf] = __builtin_amdgcn_mfma_f32_16x16x32_bf16(ah, wl[nf][ks], acc[ch][nf], 0, 0, 0);
                }
            }
        }
    }
    float bv[2] = {0.f, 0.f};
    if (matsel == 0 && bias) { bv[0] = bias[ncol + l15]; bv[1] = bias[ncol + 16 + l15]; }
    #pragma unroll
    for (int ch = 0; ch < 2; ++ch) {
        #pragma unroll
        for (int nf = 0; nf < 2; ++nf) {
            const int col = ncol + nf * 16 + l15;
            #pragma unroll
            for (int j = 0; j < 4; ++j) {
                const int row = rbase0 + ch * 16 + rowb + j;
                const float v = acc[ch][nf][j] + bv[nf];
                if (matsel == 0) Croot[(size_t)row * HH + col] = v;
                else             Crel[(size_t)row * HH + col]  = bf16rn(v);
            }
        }
    }
}

// ---------------------------------------------------------------------------
// all 5 weight splits in ONE dispatch (verified R14)
// ---------------------------------------------------------------------------
__global__ __launch_bounds__(256)
void split_all(const float* __restrict__ r1, const float* __restrict__ e1,
               const float* __restrict__ r2, const float* __restrict__ e2,
               const float* __restrict__ r3, const float* __restrict__ e3,
               const float* __restrict__ r4, const float* __restrict__ e4,
               const float* __restrict__ r5, const float* __restrict__ e5,
               ushort* __restrict__ W1h, ushort* __restrict__ W1l,
               ushort* __restrict__ W2h, ushort* __restrict__ W2l,
               ushort* __restrict__ W3h, ushort* __restrict__ W3l,
               ushort* __restrict__ W4h, ushort* __restrict__ W4l,
               ushort* __restrict__ W5h, ushort* __restrict__ W5l)
{
    const int b = blockIdx.x;
    const float *Wroot, *Wrel; int K, Kp, base; ushort *Wh, *Wl;
    if (b < 224)      { Wroot = r1; Wrel = e1; K = FIN; Kp = 224; Wh = W1h; Wl = W1l; base = 0; }
    else if (b < 352) { Wroot = r2; Wrel = e2; K = 128; Kp = 128; Wh = W2h; Wl = W2l; base = 224; }
    else if (b < 480) { Wroot = r3; Wrel = e3; K = 128; Kp = 128; Wh = W3h; Wl = W3l; base = 352; }
    else if (b < 608) { Wroot = r4; Wrel = e4; K = 128; Kp = 128; Wh = W4h; Wl = W4l; base = 480; }
    else              { Wroot = r5; Wrel = e5; K = 512; Kp = 512; Wh = W5h; Wl = W5l; base = 608; }
    const int i = (b - base) * 256 + threadIdx.x;
    const int row = i / Kp, col = i - row * Kp;
    float v = 0.f;
    if (col < K) v = (row < 128) ? Wroot[row * K + col] : Wrel[(row - 128) * K + col];
    const ushort h = bf16rn(v);
    const float hf = __uint_as_float((uint)h << 16);
    const int ksteps = Kp >> 5;
    const size_t addr = ((size_t)(row >> 4) * ksteps + (col >> 5)) * 512
                      + (size_t)(((col >> 3) & 3) * 16 + (row & 15)) * 8 + (col & 7);
    Wh[addr] = h;
    Wl[addr] = bf16rn(v - hf);
}

// ---------------------------------------------------------------------------
// pack layer-1 input (verified R12)
// ---------------------------------------------------------------------------
__global__ __launch_bounds__(448)
void pack_x(const float* __restrict__ x, ushort* __restrict__ Xh, ushort* __restrict__ Xl)
{
    const int t = threadIdx.x;
    const int n = blockIdx.x * 16 + (t & 15);
    const int o = t >> 4;                   // k-octet 0..27
    float v[8];
    if (o < 25) {
        const float4 a = *(const float4*)&x[(size_t)n * FIN + o * 8];
        const float4 b = *(const float4*)&x[(size_t)n * FIN + o * 8 + 4];
        v[0]=a.x; v[1]=a.y; v[2]=a.z; v[3]=a.w; v[4]=b.x; v[5]=b.y; v[6]=b.z; v[7]=b.w;
    } else {
        #pragma unroll
        for (int j = 0; j < 8; ++j) v[j] = 0.f;
    }
    bf16x8 h, l;
    #pragma unroll
    for (int j = 0; j < 8; ++j) {
        const ushort hh = bf16rn(v[j]);
        h[j] = (short)hh;
        l[j] = (short)bf16rn(v[j] - __uint_as_float((uint)hh << 16));
    }
    const size_t addr = ((size_t)(n >> 4) * 7 + (o >> 2)) * 512
                      + (size_t)((o & 3) * 16 + (n & 15)) * 8;
    *(bf16x8*)&Xh[addr] = h;
    *(bf16x8*)&Xl[addr] = l;
}

// ---------------------------------------------------------------------------
// CSR build (verified R12)
// ---------------------------------------------------------------------------
__global__ void hist_k(const int* __restrict__ ei, int* __restrict__ deg)
{
    int e = blockIdx.x * blockDim.x + threadIdx.x;
    if (e < EE) atomicAdd(&deg[ei[EE + e]], 1);
}

__global__ __launch_bounds__(1024)
void scan_k(const int* __restrict__ deg, int* __restrict__ row_ptr,
            int* __restrict__ pos)
{
    __shared__ int part[1024];
    const int t = threadIdx.x;
    const int chunk = (NN + 1023) / 1024;
    const int i0 = t * chunk;
    const int i1 = min(i0 + chunk, NN);
    int s = 0;
    for (int i = i0; i < i1; ++i) s += deg[i];
    part[t] = s;
    __syncthreads();
    for (int off = 1; off < 1024; off <<= 1) {
        int v = (t >= off) ? part[t - off] : 0;
        __syncthreads();
        part[t] += v;
        __syncthreads();
    }
    int run = (t == 0) ? 0 : part[t - 1];
    for (int i = i0; i < i1; ++i) {
        const int d = deg[i];
        row_ptr[i] = run;
        pos[i] = run;
        run += d;
    }
    if (t == 0) row_ptr[NN] = part[1023];
}

__global__ void fill_k(const int* __restrict__ ei, int* __restrict__ pos,
                       int* __restrict__ eidx)
{
    int e = blockIdx.x * blockDim.x + threadIdx.x;
    if (e < EE) {
        const int slot = atomicAdd(&pos[ei[EE + e]], 1);
        eidx[slot] = ei[e];
    }
}

// one zero pass over deg (ints) + STATS/POOL (floats)
__global__ void zero2_k(int* __restrict__ deg, float* __restrict__ sp, int n1, int n2)
{
    int i = blockIdx.x * blockDim.x + threadIdx.x;
    if (i < n1) deg[i] = 0;
    else if (i < n1 + n2) sp[i - n1] = 0.f;
}

// ---------------------------------------------------------------------------
// gather (R14 structure, bf16 T1 + index prefetch): LDS-staged packed writes
// ---------------------------------------------------------------------------
__global__ __launch_bounds__(512)
void gather_pk(const float* __restrict__ base, const ushort* __restrict__ T1,
               const int* __restrict__ row_ptr, const int* __restrict__ eidx,
               ushort* __restrict__ Xh, ushort* __restrict__ Xl)
{
    __shared__ ushort lds_h[16][136];
    __shared__ ushort lds_l[16][136];
    const int t   = threadIdx.x;
    const int grp = t >> 5;
    const int ln  = t & 31;
    const int n   = blockIdx.x * 16 + grp;

    const float4 r = edge_gather(base, T1, eidx, n, ln, row_ptr[n], row_ptr[n + 1]);
    float v[4];
    v[0] = fmaxf(r.x, 0.f); v[1] = fmaxf(r.y, 0.f);
    v[2] = fmaxf(r.z, 0.f); v[3] = fmaxf(r.w, 0.f);
    ushort4 h4, l4;
    {
        ushort hh; float hf;
        hh = bf16rn(v[0]); hf = __uint_as_float((uint)hh << 16); h4.x = hh; l4.x = bf16rn(v[0] - hf);
        hh = bf16rn(v[1]); hf = __uint_as_float((uint)hh << 16); h4.y = hh; l4.y = bf16rn(v[1] - hf);
        hh = bf16rn(v[2]); hf = __uint_as_float((uint)hh << 16); h4.z = hh; l4.z = bf16rn(v[2] - hf);
        hh = bf16rn(v[3]); hf = __uint_as_float((uint)hh << 16); h4.w = hh; l4.w = bf16rn(v[3] - hf);
    }
    *(ushort4*)&lds_h[grp][ln * 4] = h4;
    *(ushort4*)&lds_l[grp][ln * 4] = l4;
    __syncthreads();

    const int nl = t & 15;
    const int o  = (t >> 4) & 15;
    const size_t addr = ((size_t)blockIdx.x * 4 + (o >> 2)) * 512
                      + (size_t)((o & 3) * 16 + nl) * 8;
    if (t < 256) {
        *(uint4*)&Xh[addr] = *(const uint4*)&lds_h[nl][o * 8];
    } else {
        *(uint4*)&Xl[addr] = *(const uint4*)&lds_l[nl][o * 8];
    }
}

// ---------------------------------------------------------------------------
// layer-5 gather FUSED with BN-stats + pooling (R15-measured win), bf16 T1
// ---------------------------------------------------------------------------
__global__ __launch_bounds__(512)
void gather_bn(const float* __restrict__ base, const ushort* __restrict__ T1,
               const int* __restrict__ row_ptr, const int* __restrict__ eidx,
               const int* __restrict__ batch,
               float* __restrict__ stats, float* __restrict__ pool)
{
    __shared__ float vals[16][132];
    __shared__ int bg[16];
    const int t   = threadIdx.x;
    const int grp = t >> 5;
    const int ln  = t & 31;
    const int n0  = blockIdx.x * 16;
    const int n   = n0 + grp;

    const float4 r = edge_gather(base, T1, eidx, n, ln, row_ptr[n], row_ptr[n + 1]);
    vals[grp][ln * 4 + 0] = r.x;
    vals[grp][ln * 4 + 1] = r.y;
    vals[grp][ln * 4 + 2] = r.z;
    vals[grp][ln * 4 + 3] = r.w;
    if (t < 16) bg[t] = batch[n0 + t];
    __syncthreads();

    if (t < 128) {
        float s = 0.f;
        #pragma unroll
        for (int rr = 0; rr < 16; ++rr) s += vals[rr][t];
        atomicAdd(&stats[t], s);
    } else if (t < 256) {
        const int f = t - 128;
        float q = 0.f;
        #pragma unroll
        for (int rr = 0; rr < 16; ++rr) { const float v = vals[rr][f]; q += v * v; }
        atomicAdd(&stats[128 + f], q);
    } else if (t < 384) {
        const int f = t - 256;
        float acc = 0.f;
        int curg = bg[0];
        #pragma unroll
        for (int rr = 0; rr < 16; ++rr) {
            const int g = bg[rr];
            if (g != curg) {
                atomicAdd(&pool[(size_t)curg * HH + f], acc);
                acc = 0.f; curg = g;
            }
            acc += vals[rr][f];
        }
        atomicAdd(&pool[(size_t)curg * HH + f], acc);
    }
}

// BN affine on pooled means + linear head (verified R12)
__global__ __launch_bounds__(128)
void finalize(const float* __restrict__ stats, const float* __restrict__ pool,
              const int* __restrict__ batch,
              const float* __restrict__ gamma, const float* __restrict__ beta,
              const float* __restrict__ lin_w, const float* __restrict__ lin_b,
              float* __restrict__ out)
{
    const int g = blockIdx.x, f = threadIdx.x;
    __shared__ int seg[2];
    if (f < 2) {
        const int target = g + f;
        int lo = 0, hi = NN;
        while (lo < hi) {
            const int mid = (lo + hi) >> 1;
            if (batch[mid] < target) lo = mid + 1; else hi = mid;
        }
        seg[f] = lo;
    }
    __syncthreads();
    const float c   = (float)(seg[1] - seg[0]);
    const float mu  = stats[f] * (1.0f / NN);
    const float var = stats[128 + f] * (1.0f / NN) - mu * mu;
    const float scale = gamma[f] * rsqrtf(var + BN_EPS);
    const float pm = pool[(size_t)g * HH + f] / fmaxf(c, 1.0f);
    __shared__ float sh[128];
    sh[f] = (pm - mu) * scale + beta[f];
    __syncthreads();
    if (f < CC) {
        float s = lin_b[f];
        #pragma unroll 8
        for (int k = 0; k < HH; ++k) s += sh[k] * lin_w[f * HH + k];
        out[(size_t)g * CC + f] = s;
    }
}

extern "C" void kernel_launch(void* const* d_in, const int* in_sizes, int n_in,
                              void* d_out, int out_size, void* d_ws, size_t ws_size,
                              hipStream_t stream)
{
    const float* x       = (const float*)d_in[0];
    const int*   ei      = (const int*)d_in[1];
    const int*   batch   = (const int*)d_in[2];
    const float* w1_rel  = (const float*)d_in[3];
    const float* w1_root = (const float*)d_in[4];
    const float* b1      = (const float*)d_in[5];
    const float* w2_rel  = (const float*)d_in[6];
    const float* w2_root = (const float*)d_in[7];
    const float* b2      = (const float*)d_in[8];
    const float* w3_rel  = (const float*)d_in[9];
    const float* w3_root = (const float*)d_in[10];
    const float* b3      = (const float*)d_in[11];
    const float* w4_rel  = (const float*)d_in[12];
    const float* w4_root = (const float*)d_in[13];
    const float* b4      = (const float*)d_in[14];
    const float* w5_rel  = (const float*)d_in[15];   // [128, 512]
    const float* w5_root = (const float*)d_in[16];   // [128, 512]
    const float* b5      = (const float*)d_in[17];
    const float* gamma   = (const float*)d_in[18];
    const float* beta    = (const float*)d_in[19];
    const float* lin_w   = (const float*)d_in[20];
    const float* lin_b   = (const float*)d_in[21];
    float* out = (float*)d_out;

    const size_t NH = (size_t)NN * HH;   // 2,560,000
    float*  XR  = (float*)d_ws;
    float*  T1SPACE = XR + NH;           // NH floats reserved; bf16 T1 uses half
    ushort* T1  = (ushort*)T1SPACE;
    ushort* X1h = (ushort*)(T1SPACE + NH);
    ushort* X1l = X1h + NH;
    ushort* X2h = X1l + NH;
    ushort* X2l = X2h + NH;
    ushort* X3h = X2l + NH;
    ushort* X3l = X3h + NH;
    ushort* X4h = X3l + NH;
    ushort* X4l = X4h + NH;
    const int K1P = 224;
    ushort* W1h = X4l + NH;
    ushort* W1l = W1h + 256 * K1P;
    ushort* W2h = W1l + 256 * K1P;
    ushort* W2l = W2h + 256 * 128;
    ushort* W3h = W2l + 256 * 128;
    ushort* W3l = W3h + 256 * 128;
    ushort* W4h = W3l + 256 * 128;
    ushort* W4l = W4h + 256 * 128;
    ushort* W5h = W4l + 256 * 128;
    ushort* W5l = W5h + 256 * 512;
    float*  STATS = (float*)(W5l + 256 * 512);   // 256
    float*  POOL  = STATS + 256;                 // GG*HH
    int* row_ptr = (int*)(POOL + (size_t)GG * HH);
    int* pos     = row_ptr + (NN + 1);
    int* deg     = pos + NN;
    int* eidx    = deg + NN;
    const size_t need = (size_t)(eidx + EE) - (size_t)d_ws;
    if (ws_size < need) return;

    // packed layer-1 input aliases X2h..X3l (dead once L1 GEMM completes)
    ushort* XPh = X2h;
    ushort* XPl = X2h + (size_t)NN * K1P;

    const dim3 blk(256);
    const int ggw   = NN / RPB;             // 625 blocks x 512 thr
    const int gedge = (EE + 255) / 256;
    const int ggpk  = NN / 16;              // 1250 blocks

    // single zero pass: deg (ints) + STATS/POOL (floats)
    const int nz = NN + 256 + GG * HH;
    zero2_k<<<(nz + 255) / 256, blk, 0, stream>>>(deg, STATS, NN, 256 + GG * HH);

    // CSR build
    hist_k<<<gedge, blk, 0, stream>>>(ei, deg);
    scan_k<<<1, dim3(1024), 0, stream>>>(deg, row_ptr, pos);
    fill_k<<<gedge, blk, 0, stream>>>(ei, pos, eidx);

    // all weight splits in one dispatch + layer-1 input pack
    split_all<<<1120, blk, 0, stream>>>(w1_root, w1_rel, w2_root, w2_rel,
                                        w3_root, w3_rel, w4_root, w4_rel,
                                        w5_root, w5_rel,
                                        W1h, W1l, W2h, W2l, W3h, W3l,
                                        W4h, W4l, W5h, W5l);
    pack_x<<<ggpk, dim3(448), 0, stream>>>(x, XPh, XPl);

    // layer 1 (K=224 packed)
    gemm_pk<7><<<ggw, dim3(512), 0, stream>>>(XPh, XPl, W1h, W1l, b1, XR, T1);
    gather_pk<<<ggpk, dim3(512), 0, stream>>>(XR, T1, row_ptr, eidx, X1h, X1l);
    // layers 2-4 (K=128 packed)
    gemm_pk<4><<<ggw, dim3(512), 0, stream>>>(X1h, X1l, W2h, W2l, b2, XR, T1);
    gather_pk<<<ggpk, dim3(512), 0, stream>>>(XR, T1, row_ptr, eidx, X2h, X2l);
    gemm_pk<4><<<ggw, dim3(512), 0, stream>>>(X2h, X2l, W3h, W3l, b3, XR, T1);
    gather_pk<<<ggpk, dim3(512), 0, stream>>>(XR, T1, row_ptr, eidx, X3h, X3l);
    gemm_pk<4><<<ggw, dim3(512), 0, stream>>>(X3h, X3l, W4h, W4l, b4, XR, T1);
    gather_pk<<<ggpk, dim3(512), 0, stream>>>(XR, T1, row_ptr, eidx, X4h, X4l);
    // layer 5: packed concat GEMM, then fused gather+BN+pool (X5 never stored)
    gemm_pk4<<<ggw, dim3(512), 0, stream>>>(X1h, X1l, X2h, X2l, X3h, X3l, X4h, X4l,
                                            W5h, W5l, b5, XR, T1);
    gather_bn<<<ggpk, dim3(512), 0, stream>>>(XR, T1, row_ptr, eidx, batch, STATS, POOL);

    // epilogue
    finalize<<<GG, dim3(128), 0, stream>>>(STATS, POOL, batch, gamma, beta, lin_w, lin_b, out);
}

// Round 19
// 278.323 us; speedup vs baseline: 1.1865x; 1.0247x over previous
//
#include <hip/hip_runtime.h>

#define NN 20000
#define EE 320000
#define FIN 200
#define HH 128
#define CC 10
#define GG 100
#define BN_EPS 1e-5f
#define RPB 32          // rows per gemm block; 625 blocks x 32 = 20000 exact

typedef __attribute__((ext_vector_type(8))) short bf16x8;
typedef __attribute__((ext_vector_type(4))) float f32x4;

__device__ __forceinline__ ushort bf16rn(float x) {
    uint u = __float_as_uint(x);
    u += 0x7FFFu + ((u >> 16) & 1u);
    return (ushort)(u >> 16);
}
__device__ __forceinline__ float bf2f(ushort u) {
    return __uint_as_float((uint)u << 16);
}

// 4-deep edge aggregation over bf16 T1 rows + index prefetch (R18-proven).
__device__ __forceinline__
float4 edge_gather(const float* __restrict__ base, const ushort* __restrict__ T1,
                   const int* __restrict__ eidx, int n, int ln, int e0, int e1)
{
    float4 a0 = *(const float4*)&base[(size_t)n * HH + ln * 4];
    float4 a1 = {0,0,0,0}, a2 = {0,0,0,0}, a3 = {0,0,0,0};
    int e = e0;
    int s0, s1, s2, s3;
    if (e + 4 <= e1) { s0 = eidx[e]; s1 = eidx[e+1]; s2 = eidx[e+2]; s3 = eidx[e+3]; }
    while (e + 4 <= e1) {
        const ushort4 u0 = *(const ushort4*)&T1[(size_t)s0 * HH + ln * 4];
        const ushort4 u1 = *(const ushort4*)&T1[(size_t)s1 * HH + ln * 4];
        const ushort4 u2 = *(const ushort4*)&T1[(size_t)s2 * HH + ln * 4];
        const ushort4 u3 = *(const ushort4*)&T1[(size_t)s3 * HH + ln * 4];
        e += 4;
        if (e + 4 <= e1) {
            s0 = eidx[e]; s1 = eidx[e+1]; s2 = eidx[e+2]; s3 = eidx[e+3];
        }
        a0.x += bf2f(u0.x); a0.y += bf2f(u0.y); a0.z += bf2f(u0.z); a0.w += bf2f(u0.w);
        a1.x += bf2f(u1.x); a1.y += bf2f(u1.y); a1.z += bf2f(u1.z); a1.w += bf2f(u1.w);
        a2.x += bf2f(u2.x); a2.y += bf2f(u2.y); a2.z += bf2f(u2.z); a2.w += bf2f(u2.w);
        a3.x += bf2f(u3.x); a3.y += bf2f(u3.y); a3.z += bf2f(u3.z); a3.w += bf2f(u3.w);
    }
    for (; e < e1; ++e) {
        const int s = eidx[e];
        const ushort4 u = *(const ushort4*)&T1[(size_t)s * HH + ln * 4];
        a0.x += bf2f(u.x); a0.y += bf2f(u.y); a0.z += bf2f(u.z); a0.w += bf2f(u.w);
    }
    float4 r;
    r.x = (a0.x + a1.x) + (a2.x + a3.x);
    r.y = (a0.y + a1.y) + (a2.y + a3.y);
    r.z = (a0.z + a1.z) + (a2.z + a3.z);
    r.w = (a0.w + a1.w) + (a2.w + a3.w);
    return r;
}

// Fragment-major packing (verified R11/R12):
// elem (r,k) -> ((r>>4)*(K/32) + (k>>5))*512 + (((k>>3)&3)*16 + (r&15))*8 + (k&7)

// ---------------------------------------------------------------------------
// Packed W-in-registers GEMM. ALO: activation lo-limb present (layer 1 only;
// layers 2-5 activations are already ~2^-9 noisy from bf16 T1, so their lo
// limb is dropped: A*W = Ah*Wh + Ah*Wl (+ ALO: Al*Wh)).
// Croot fp32 (+bias), Crel bf16 (T1).
// ---------------------------------------------------------------------------
template<int KSTEPS, bool ALO>
__global__ __launch_bounds__(512)
void gemm_pk(const ushort* __restrict__ Aph, const ushort* __restrict__ Apl,
             const ushort* __restrict__ Wph, const ushort* __restrict__ Wpl,
             const float* __restrict__ bias,
             float* __restrict__ Croot, ushort* __restrict__ Crel)
{
    const int wid  = threadIdx.x >> 6;
    const int lane = threadIdx.x & 63;
    const int l15  = lane & 15;
    const int matsel = wid >> 2;
    const int ncol = (wid & 3) * 32;
    const int wrg0 = matsel * 8 + (ncol >> 4);
    const int rowb = (lane >> 4) * 4;
    const int rbase0 = blockIdx.x * RPB;

    bf16x8 wh[2][KSTEPS], wl[2][KSTEPS];
    #pragma unroll
    for (int nf = 0; nf < 2; ++nf) {
        const size_t wbase = (size_t)(wrg0 + nf) * KSTEPS * 512;
        #pragma unroll
        for (int ks = 0; ks < KSTEPS; ++ks) {
            wh[nf][ks] = *(const bf16x8*)&Wph[wbase + (size_t)(ks * 64 + lane) * 8];
            wl[nf][ks] = *(const bf16x8*)&Wpl[wbase + (size_t)(ks * 64 + lane) * 8];
        }
    }
    float bv[2] = {0.f, 0.f};
    if (matsel == 0 && bias) { bv[0] = bias[ncol + l15]; bv[1] = bias[ncol + 16 + l15]; }

    #pragma unroll
    for (int ch = 0; ch < RPB; ch += 16) {
        const size_t abase = (size_t)((rbase0 + ch) >> 4) * KSTEPS * 512;
        f32x4 acc[2] = {};
        #pragma unroll
        for (int ks = 0; ks < KSTEPS; ++ks) {
            const bf16x8 ah = *(const bf16x8*)&Aph[abase + (size_t)(ks * 64 + lane) * 8];
            bf16x8 al;
            if (ALO) al = *(const bf16x8*)&Apl[abase + (size_t)(ks * 64 + lane) * 8];
            #pragma unroll
            for (int nf = 0; nf < 2; ++nf) {
                acc[nf] = __builtin_amdgcn_mfma_f32_16x16x32_bf16(ah, wh[nf][ks], acc[nf], 0, 0, 0);
                acc[nf] = __builtin_amdgcn_mfma_f32_16x16x32_bf16(ah, wl[nf][ks], acc[nf], 0, 0, 0);
                if (ALO)
                    acc[nf] = __builtin_amdgcn_mfma_f32_16x16x32_bf16(al, wh[nf][ks], acc[nf], 0, 0, 0);
            }
        }
        #pragma unroll
        for (int nf = 0; nf < 2; ++nf) {
            const int col = ncol + nf * 16 + l15;   // LOCAL column (0..127)
            #pragma unroll
            for (int j = 0; j < 4; ++j) {
                const int row = rbase0 + ch + rowb + j;
                const float v = acc[nf][j] + bv[nf];
                if (matsel == 0) Croot[(size_t)row * HH + col] = v;
                else             Crel[(size_t)row * HH + col]  = bf16rn(v);
            }
        }
    }
}

// ---------------------------------------------------------------------------
// Layer-5 packed concat-GEMM: A hi-limb only, W hi+lo. RPB=32 (2 chunks).
// ---------------------------------------------------------------------------
__global__ __launch_bounds__(512)
void gemm_pk4(const ushort* __restrict__ X1h, const ushort* __restrict__ X2h,
              const ushort* __restrict__ X3h, const ushort* __restrict__ X4h,
              const ushort* __restrict__ Wph, const ushort* __restrict__ Wpl,
              const float* __restrict__ bias,
              float* __restrict__ Croot, ushort* __restrict__ Crel)
{
    const int wid  = threadIdx.x >> 6;
    const int lane = threadIdx.x & 63;
    const int l15  = lane & 15;
    const int matsel = wid >> 2;
    const int ncol = (wid & 3) * 32;
    const int wrg0 = matsel * 8 + (ncol >> 4);
    const int rowb = (lane >> 4) * 4;
    const int rbase0 = blockIdx.x * RPB;
    const ushort* const Ahs[4] = {X1h, X2h, X3h, X4h};

    f32x4 acc[2][2] = {};
    #pragma unroll
    for (int src = 0; src < 4; ++src) {
        const ushort* __restrict__ Ah_ = Ahs[src];
        bf16x8 wh[2][4], wl[2][4];
        #pragma unroll
        for (int nf = 0; nf < 2; ++nf) {
            const size_t wbase = ((size_t)(wrg0 + nf) * 16 + src * 4) * 512;
            #pragma unroll
            for (int ks = 0; ks < 4; ++ks) {
                wh[nf][ks] = *(const bf16x8*)&Wph[wbase + (size_t)(ks * 64 + lane) * 8];
                wl[nf][ks] = *(const bf16x8*)&Wpl[wbase + (size_t)(ks * 64 + lane) * 8];
            }
        }
        #pragma unroll
        for (int ch = 0; ch < 2; ++ch) {
            const size_t abase = (size_t)((rbase0 + ch * 16) >> 4) * 4 * 512;
            #pragma unroll
            for (int ks = 0; ks < 4; ++ks) {
                const bf16x8 ah = *(const bf16x8*)&Ah_[abase + (size_t)(ks * 64 + lane) * 8];
                #pragma unroll
                for (int nf = 0; nf < 2; ++nf) {
                    acc[ch][nf] = __builtin_amdgcn_mfma_f32_16x16x32_bf16(ah, wh[nf][ks], acc[ch][nf], 0, 0, 0);
                    acc[ch][nf] = __builtin_amdgcn_mfma_f32_16x16x32_bf16(ah, wl[nf][ks], acc[ch][nf], 0, 0, 0);
                }
            }
        }
    }
    float bv[2] = {0.f, 0.f};
    if (matsel == 0 && bias) { bv[0] = bias[ncol + l15]; bv[1] = bias[ncol + 16 + l15]; }
    #pragma unroll
    for (int ch = 0; ch < 2; ++ch) {
        #pragma unroll
        for (int nf = 0; nf < 2; ++nf) {
            const int col = ncol + nf * 16 + l15;
            #pragma unroll
            for (int j = 0; j < 4; ++j) {
                const int row = rbase0 + ch * 16 + rowb + j;
                const float v = acc[ch][nf][j] + bv[nf];
                if (matsel == 0) Croot[(size_t)row * HH + col] = v;
                else             Crel[(size_t)row * HH + col]  = bf16rn(v);
            }
        }
    }
}

// ---------------------------------------------------------------------------
// all 5 weight splits in ONE dispatch (verified R14)
// ---------------------------------------------------------------------------
__global__ __launch_bounds__(256)
void split_all(const float* __restrict__ r1, const float* __restrict__ e1,
               const float* __restrict__ r2, const float* __restrict__ e2,
               const float* __restrict__ r3, const float* __restrict__ e3,
               const float* __restrict__ r4, const float* __restrict__ e4,
               const float* __restrict__ r5, const float* __restrict__ e5,
               ushort* __restrict__ W1h, ushort* __restrict__ W1l,
               ushort* __restrict__ W2h, ushort* __restrict__ W2l,
               ushort* __restrict__ W3h, ushort* __restrict__ W3l,
               ushort* __restrict__ W4h, ushort* __restrict__ W4l,
               ushort* __restrict__ W5h, ushort* __restrict__ W5l)
{
    const int b = blockIdx.x;
    const float *Wroot, *Wrel; int K, Kp, base; ushort *Wh, *Wl;
    if (b < 224)      { Wroot = r1; Wrel = e1; K = FIN; Kp = 224; Wh = W1h; Wl = W1l; base = 0; }
    else if (b < 352) { Wroot = r2; Wrel = e2; K = 128; Kp = 128; Wh = W2h; Wl = W2l; base = 224; }
    else if (b < 480) { Wroot = r3; Wrel = e3; K = 128; Kp = 128; Wh = W3h; Wl = W3l; base = 352; }
    else if (b < 608) { Wroot = r4; Wrel = e4; K = 128; Kp = 128; Wh = W4h; Wl = W4l; base = 480; }
    else              { Wroot = r5; Wrel = e5; K = 512; Kp = 512; Wh = W5h; Wl = W5l; base = 608; }
    const int i = (b - base) * 256 + threadIdx.x;
    const int row = i / Kp, col = i - row * Kp;
    float v = 0.f;
    if (col < K) v = (row < 128) ? Wroot[row * K + col] : Wrel[(row - 128) * K + col];
    const ushort h = bf16rn(v);
    const float hf = __uint_as_float((uint)h << 16);
    const int ksteps = Kp >> 5;
    const size_t addr = ((size_t)(row >> 4) * ksteps + (col >> 5)) * 512
                      + (size_t)(((col >> 3) & 3) * 16 + (row & 15)) * 8 + (col & 7);
    Wh[addr] = h;
    Wl[addr] = bf16rn(v - hf);
}

// ---------------------------------------------------------------------------
// pack layer-1 input (verified R12; layer 1 keeps hi+lo: x is exact fp32)
// ---------------------------------------------------------------------------
__global__ __launch_bounds__(448)
void pack_x(const float* __restrict__ x, ushort* __restrict__ Xh, ushort* __restrict__ Xl)
{
    const int t = threadIdx.x;
    const int n = blockIdx.x * 16 + (t & 15);
    const int o = t >> 4;                   // k-octet 0..27
    float v[8];
    if (o < 25) {
        const float4 a = *(const float4*)&x[(size_t)n * FIN + o * 8];
        const float4 b = *(const float4*)&x[(size_t)n * FIN + o * 8 + 4];
        v[0]=a.x; v[1]=a.y; v[2]=a.z; v[3]=a.w; v[4]=b.x; v[5]=b.y; v[6]=b.z; v[7]=b.w;
    } else {
        #pragma unroll
        for (int j = 0; j < 8; ++j) v[j] = 0.f;
    }
    bf16x8 h, l;
    #pragma unroll
    for (int j = 0; j < 8; ++j) {
        const ushort hh = bf16rn(v[j]);
        h[j] = (short)hh;
        l[j] = (short)bf16rn(v[j] - __uint_as_float((uint)hh << 16));
    }
    const size_t addr = ((size_t)(n >> 4) * 7 + (o >> 2)) * 512
                      + (size_t)((o & 3) * 16 + (n & 15)) * 8;
    *(bf16x8*)&Xh[addr] = h;
    *(bf16x8*)&Xl[addr] = l;
}

// ---------------------------------------------------------------------------
// CSR build (verified R12)
// ---------------------------------------------------------------------------
__global__ void hist_k(const int* __restrict__ ei, int* __restrict__ deg)
{
    int e = blockIdx.x * blockDim.x + threadIdx.x;
    if (e < EE) atomicAdd(&deg[ei[EE + e]], 1);
}

__global__ __launch_bounds__(1024)
void scan_k(const int* __restrict__ deg, int* __restrict__ row_ptr,
            int* __restrict__ pos)
{
    __shared__ int part[1024];
    const int t = threadIdx.x;
    const int chunk = (NN + 1023) / 1024;
    const int i0 = t * chunk;
    const int i1 = min(i0 + chunk, NN);
    int s = 0;
    for (int i = i0; i < i1; ++i) s += deg[i];
    part[t] = s;
    __syncthreads();
    for (int off = 1; off < 1024; off <<= 1) {
        int v = (t >= off) ? part[t - off] : 0;
        __syncthreads();
        part[t] += v;
        __syncthreads();
    }
    int run = (t == 0) ? 0 : part[t - 1];
    for (int i = i0; i < i1; ++i) {
        const int d = deg[i];
        row_ptr[i] = run;
        pos[i] = run;
        run += d;
    }
    if (t == 0) row_ptr[NN] = part[1023];
}

__global__ void fill_k(const int* __restrict__ ei, int* __restrict__ pos,
                       int* __restrict__ eidx)
{
    int e = blockIdx.x * blockDim.x + threadIdx.x;
    if (e < EE) {
        const int slot = atomicAdd(&pos[ei[EE + e]], 1);
        eidx[slot] = ei[e];
    }
}

// one zero pass over deg (ints) + STATS/POOL (floats)
__global__ void zero2_k(int* __restrict__ deg, float* __restrict__ sp, int n1, int n2)
{
    int i = blockIdx.x * blockDim.x + threadIdx.x;
    if (i < n1) deg[i] = 0;
    else if (i < n1 + n2) sp[i - n1] = 0.f;
}

// ---------------------------------------------------------------------------
// gather: bf16 T1 reads + ReLU + hi-only bf16 pack (lo dropped: activation is
// already ~2^-9 noisy from T1 quantization). LDS-staged coalesced writes.
// ---------------------------------------------------------------------------
__global__ __launch_bounds__(512)
void gather_pk(const float* __restrict__ base, const ushort* __restrict__ T1,
               const int* __restrict__ row_ptr, const int* __restrict__ eidx,
               ushort* __restrict__ Xh)
{
    __shared__ ushort lds_h[16][136];
    const int t   = threadIdx.x;
    const int grp = t >> 5;
    const int ln  = t & 31;
    const int n   = blockIdx.x * 16 + grp;

    const float4 r = edge_gather(base, T1, eidx, n, ln, row_ptr[n], row_ptr[n + 1]);
    ushort4 h4;
    h4.x = bf16rn(fmaxf(r.x, 0.f));
    h4.y = bf16rn(fmaxf(r.y, 0.f));
    h4.z = bf16rn(fmaxf(r.z, 0.f));
    h4.w = bf16rn(fmaxf(r.w, 0.f));
    *(ushort4*)&lds_h[grp][ln * 4] = h4;
    __syncthreads();

    if (t < 256) {
        const int nl = t & 15;
        const int o  = (t >> 4) & 15;
        const size_t addr = ((size_t)blockIdx.x * 4 + (o >> 2)) * 512
                          + (size_t)((o & 3) * 16 + nl) * 8;
        *(uint4*)&Xh[addr] = *(const uint4*)&lds_h[nl][o * 8];
    }
}

// ---------------------------------------------------------------------------
// layer-5 gather FUSED with BN-stats + pooling (R15-measured win), bf16 T1
// ---------------------------------------------------------------------------
__global__ __launch_bounds__(512)
void gather_bn(const float* __restrict__ base, const ushort* __restrict__ T1,
               const int* __restrict__ row_ptr, const int* __restrict__ eidx,
               const int* __restrict__ batch,
               float* __restrict__ stats, float* __restrict__ pool)
{
    __shared__ float vals[16][132];
    __shared__ int bg[16];
    const int t   = threadIdx.x;
    const int grp = t >> 5;
    const int ln  = t & 31;
    const int n0  = blockIdx.x * 16;
    const int n   = n0 + grp;

    const float4 r = edge_gather(base, T1, eidx, n, ln, row_ptr[n], row_ptr[n + 1]);
    vals[grp][ln * 4 + 0] = r.x;
    vals[grp][ln * 4 + 1] = r.y;
    vals[grp][ln * 4 + 2] = r.z;
    vals[grp][ln * 4 + 3] = r.w;
    if (t < 16) bg[t] = batch[n0 + t];
    __syncthreads();

    if (t < 128) {
        float s = 0.f;
        #pragma unroll
        for (int rr = 0; rr < 16; ++rr) s += vals[rr][t];
        atomicAdd(&stats[t], s);
    } else if (t < 256) {
        const int f = t - 128;
        float q = 0.f;
        #pragma unroll
        for (int rr = 0; rr < 16; ++rr) { const float v = vals[rr][f]; q += v * v; }
        atomicAdd(&stats[128 + f], q);
    } else if (t < 384) {
        const int f = t - 256;
        float acc = 0.f;
        int curg = bg[0];
        #pragma unroll
        for (int rr = 0; rr < 16; ++rr) {
            const int g = bg[rr];
            if (g != curg) {
                atomicAdd(&pool[(size_t)curg * HH + f], acc);
                acc = 0.f; curg = g;
            }
            acc += vals[rr][f];
        }
        atomicAdd(&pool[(size_t)curg * HH + f], acc);
    }
}

// BN affine on pooled means + linear head (verified R12)
__global__ __launch_bounds__(128)
void finalize(const float* __restrict__ stats, const float* __restrict__ pool,
              const int* __restrict__ batch,
              const float* __restrict__ gamma, const float* __restrict__ beta,
              const float* __restrict__ lin_w, const float* __restrict__ lin_b,
              float* __restrict__ out)
{
    const int g = blockIdx.x, f = threadIdx.x;
    __shared__ int seg[2];
    if (f < 2) {
        const int target = g + f;
        int lo = 0, hi = NN;
        while (lo < hi) {
            const int mid = (lo + hi) >> 1;
            if (batch[mid] < target) lo = mid + 1; else hi = mid;
        }
        seg[f] = lo;
    }
    __syncthreads();
    const float c   = (float)(seg[1] - seg[0]);
    const float mu  = stats[f] * (1.0f / NN);
    const float var = stats[128 + f] * (1.0f / NN) - mu * mu;
    const float scale = gamma[f] * rsqrtf(var + BN_EPS);
    const float pm = pool[(size_t)g * HH + f] / fmaxf(c, 1.0f);
    __shared__ float sh[128];
    sh[f] = (pm - mu) * scale + beta[f];
    __syncthreads();
    if (f < CC) {
        float s = lin_b[f];
        #pragma unroll 8
        for (int k = 0; k < HH; ++k) s += sh[k] * lin_w[f * HH + k];
        out[(size_t)g * CC + f] = s;
    }
}

extern "C" void kernel_launch(void* const* d_in, const int* in_sizes, int n_in,
                              void* d_out, int out_size, void* d_ws, size_t ws_size,
                              hipStream_t stream)
{
    const float* x       = (const float*)d_in[0];
    const int*   ei      = (const int*)d_in[1];
    const int*   batch   = (const int*)d_in[2];
    const float* w1_rel  = (const float*)d_in[3];
    const float* w1_root = (const float*)d_in[4];
    const float* b1      = (const float*)d_in[5];
    const float* w2_rel  = (const float*)d_in[6];
    const float* w2_root = (const float*)d_in[7];
    const float* b2      = (const float*)d_in[8];
    const float* w3_rel  = (const float*)d_in[9];
    const float* w3_root = (const float*)d_in[10];
    const float* b3      = (const float*)d_in[11];
    const float* w4_rel  = (const float*)d_in[12];
    const float* w4_root = (const float*)d_in[13];
    const float* b4      = (const float*)d_in[14];
    const float* w5_rel  = (const float*)d_in[15];   // [128, 512]
    const float* w5_root = (const float*)d_in[16];   // [128, 512]
    const float* b5      = (const float*)d_in[17];
    const float* gamma   = (const float*)d_in[18];
    const float* beta    = (const float*)d_in[19];
    const float* lin_w   = (const float*)d_in[20];
    const float* lin_b   = (const float*)d_in[21];
    float* out = (float*)d_out;

    const size_t NH = (size_t)NN * HH;   // 2,560,000
    const int K1P = 224;
    float*  XR  = (float*)d_ws;                  // NH floats
    ushort* T1  = (ushort*)(XR + NH);            // NH ushorts
    ushort* X1h = T1 + NH;
    ushort* X2h = X1h + NH;
    ushort* X3h = X2h + NH;
    ushort* X4h = X3h + NH;
    ushort* XPh = X4h + NH;                      // NN*K1P
    ushort* XPl = XPh + (size_t)NN * K1P;        // NN*K1P
    ushort* W1h = XPl + (size_t)NN * K1P;
    ushort* W1l = W1h + 256 * K1P;
    ushort* W2h = W1l + 256 * K1P;
    ushort* W2l = W2h + 256 * 128;
    ushort* W3h = W2l + 256 * 128;
    ushort* W3l = W3h + 256 * 128;
    ushort* W4h = W3l + 256 * 128;
    ushort* W4l = W4h + 256 * 128;
    ushort* W5h = W4l + 256 * 128;
    ushort* W5l = W5h + 256 * 512;
    float*  STATS = (float*)(W5l + 256 * 512);   // 256
    float*  POOL  = STATS + 256;                 // GG*HH
    int* row_ptr = (int*)(POOL + (size_t)GG * HH);
    int* pos     = row_ptr + (NN + 1);
    int* deg     = pos + NN;
    int* eidx    = deg + NN;
    const size_t need = (size_t)(eidx + EE) - (size_t)d_ws;
    if (ws_size < need) return;

    const dim3 blk(256);
    const int ggw   = NN / RPB;             // 625 blocks x 512 thr
    const int gedge = (EE + 255) / 256;
    const int ggpk  = NN / 16;              // 1250 blocks

    // single zero pass: deg (ints) + STATS/POOL (floats)
    const int nz = NN + 256 + GG * HH;
    zero2_k<<<(nz + 255) / 256, blk, 0, stream>>>(deg, STATS, NN, 256 + GG * HH);

    // CSR build
    hist_k<<<gedge, blk, 0, stream>>>(ei, deg);
    scan_k<<<1, dim3(1024), 0, stream>>>(deg, row_ptr, pos);
    fill_k<<<gedge, blk, 0, stream>>>(ei, pos, eidx);

    // all weight splits in one dispatch + layer-1 input pack
    split_all<<<1120, blk, 0, stream>>>(w1_root, w1_rel, w2_root, w2_rel,
                                        w3_root, w3_rel, w4_root, w4_rel,
                                        w5_root, w5_rel,
                                        W1h, W1l, W2h, W2l, W3h, W3l,
                                        W4h, W4l, W5h, W5l);
    pack_x<<<ggpk, dim3(448), 0, stream>>>(x, XPh, XPl);

    // layer 1 (K=224 packed, full hi/lo activations)
    gemm_pk<7, true ><<<ggw, dim3(512), 0, stream>>>(XPh, XPl, W1h, W1l, b1, XR, T1);
    gather_pk<<<ggpk, dim3(512), 0, stream>>>(XR, T1, row_ptr, eidx, X1h);
    // layers 2-4 (K=128 packed, hi-only activations)
    gemm_pk<4, false><<<ggw, dim3(512), 0, stream>>>(X1h, nullptr, W2h, W2l, b2, XR, T1);
    gather_pk<<<ggpk, dim3(512), 0, stream>>>(XR, T1, row_ptr, eidx, X2h);
    gemm_pk<4, false><<<ggw, dim3(512), 0, stream>>>(X2h, nullptr, W3h, W3l, b3, XR, T1);
    gather_pk<<<ggpk, dim3(512), 0, stream>>>(XR, T1, row_ptr, eidx, X3h);
    gemm_pk<4, false><<<ggw, dim3(512), 0, stream>>>(X3h, nullptr, W4h, W4l, b4, XR, T1);
    gather_pk<<<ggpk, dim3(512), 0, stream>>>(XR, T1, row_ptr, eidx, X4h);
    // layer 5: packed concat GEMM (A hi-only), then fused gather+BN+pool
    gemm_pk4<<<ggw, dim3(512), 0, stream>>>(X1h, X2h, X3h, X4h,
                                            W5h, W5l, b5, XR, T1);
    gather_bn<<<ggpk, dim3(512), 0, stream>>>(XR, T1, row_ptr, eidx, batch, STATS, POOL);

    // epilogue
    finalize<<<GG, dim3(128), 0, stream>>>(STATS, POOL, batch, gamma, beta, lin_w, lin_b, out);
}